// Round 1
// baseline (310.766 us; speedup 1.0000x reference)
//
#include <hip/hip_runtime.h>
#include <stdint.h>

// ---------------------------------------------------------------------------
// HAN forward on MI355X (gfx950).  Pipeline:
//  1) convert emb/weights to bf16 (emb padded per-node 300->320, KPAD=960)
//  2) hs = gather(emb,he_kg)@Wk^T + bk   (MFMA GEMM, fused gather staging)
//     hq = gather(emb,he_q )@Wq^T + bq
//  3) hsT[b][c][s] transpose (LDS-tiled)
//  4) logits[b][h*16+q][s] = sum_c (hq*W_h) * hs  -> per-(b,h) softmax -> att
//     (h2att_b dropped: uniform shift per head is softmax-invariant)
//  5) t = att@hs (via hsT), pooled[b,h,c] = sum_q hq[q,c]*t[h,q,c]  (fused)
//  6) fc split-K partials; 7) +fc_b -> bf16; 8) sim = out@glove^T; 9) logsoftmax
// Workspace: ~189 MB laid out below.
// ---------------------------------------------------------------------------

typedef short s16x8 __attribute__((ext_vector_type(8)));
typedef float f32x4 __attribute__((ext_vector_type(4)));

#define ASYNC_CP16(gsrc, ldst)                                                  \
  __builtin_amdgcn_global_load_lds(                                             \
      (const __attribute__((address_space(1))) void*)(gsrc),                    \
      (__attribute__((address_space(3))) void*)(ldst), 16, 0, 0)

__device__ __forceinline__ float bfr2f(uint16_t u) {
  return __builtin_bit_cast(float, (uint32_t)u << 16);
}
__device__ __forceinline__ uint16_t f2bfr(float f) {
  uint32_t u = __builtin_bit_cast(uint32_t, f);
  u += 0x7fffu + ((u >> 16) & 1u);   // RNE
  return (uint16_t)(u >> 16);
}

// ---------------- conversion kernels ----------------

// [rows][300] f32 -> [rows_out][320] bf16, zero-padded (emb / k2h_w / q2h_w / glove)
__global__ __launch_bounds__(256) void cvt_pad300(const float* __restrict__ src,
                                                  uint16_t* __restrict__ dst,
                                                  int rows_out, int rows_src) {
  int idx = blockIdx.x * 256 + threadIdx.x;
  if (idx >= rows_out * 80) return;
  int r = idx / 80, j = idx % 80;
  float4 v = make_float4(0.f, 0.f, 0.f, 0.f);
  if (r < rows_src && j < 75) v = *(const float4*)(src + (size_t)r * 300 + j * 4);
  ushort4 o;
  o.x = f2bfr(v.x); o.y = f2bfr(v.y); o.z = f2bfr(v.z); o.w = f2bfr(v.w);
  *(ushort4*)(dst + (size_t)r * 320 + j * 4) = o;
}

__global__ __launch_bounds__(256) void cvt_plain(const float* __restrict__ src,
                                                 uint16_t* __restrict__ dst, int n) {
  int i = blockIdx.x * 256 + threadIdx.x;
  if (i < n) dst[i] = f2bfr(src[i]);
}

// fc_w [300][8192] f32 -> [384][8192] bf16 (rows >=300 zero)
__global__ __launch_bounds__(256) void cvt_fc(const float* __restrict__ src,
                                              uint16_t* __restrict__ dst) {
  int i4 = blockIdx.x * 256 + threadIdx.x;  // < 384*2048
  int pos = i4 * 4;
  int r = pos >> 13, c = pos & 8191;
  float4 v = make_float4(0.f, 0.f, 0.f, 0.f);
  if (r < 300) v = *(const float4*)(src + (size_t)r * 8192 + c);
  ushort4 o;
  o.x = f2bfr(v.x); o.y = f2bfr(v.y); o.z = f2bfr(v.z); o.w = f2bfr(v.w);
  *(ushort4*)(dst + (size_t)r * 8192 + c) = o;
}

// ---------------- generic 128x128 bf16 MFMA GEMM, C = A @ Bt^T ----------------
// AMODE: 0 = A is [M][lda] bf16 matrix; 1 = A rows gathered from emb via he
// EPI:   0 = +bias[n] -> bf16 store (ldc)
//        1 = pooled: p = D * hq[q,c]; pooled[b,h,c] = sum_q p   (m = h*16+q)
//        2 = f32 store with col guard (gn < nmax), batch stride strideCf
template <int AMODE, int EPI>
__global__ __launch_bounds__(256) void gemm_bt128(
    const uint16_t* __restrict__ A, int lda, long strideAb,
    const int* __restrict__ he, const uint16_t* __restrict__ emb,
    const uint16_t* __restrict__ Bt, int ldb, long strideBb,
    int ksteps, int kchunk,
    const float* __restrict__ bias,
    uint16_t* __restrict__ Cbf, int ldc,
    float* __restrict__ Cf, int ldcf, int nmax, long strideCf,
    const uint16_t* __restrict__ hqp, long strideHq,
    uint16_t* __restrict__ pooled) {
  extern __shared__ char smem[];
  uint16_t* sA = (uint16_t*)smem;            // [128][32]
  uint16_t* sB = (uint16_t*)(smem + 8192);   // [128][32]
  int* sIdx = (int*)(smem + 16384);          // [128*3]   (AMODE==1)
  float* sTile = (float*)(smem + 16384);     // [128][128] (EPI==1)

  const int t = threadIdx.x;
  const int lane = t & 63, wave = t >> 6;
  const int wr = wave >> 1, wc = wave & 1;
  const int fr = lane & 15, fq = lane >> 4;
  const int srow = t >> 2, skg = t & 3;
  const int m0 = blockIdx.y * 128, n0 = blockIdx.x * 128;
  const int zb = blockIdx.z;

  const uint16_t* Ab = (AMODE == 0) ? (A + (long)zb * strideAb) : nullptr;
  const uint16_t* Bb = Bt + (long)zb * strideBb;

  if (AMODE == 1)
    for (int i = t; i < 384; i += 256) sIdx[i] = he[(long)m0 * 3 + i];

  f32x4 zv = {0.f, 0.f, 0.f, 0.f};
  f32x4 acc[4][4];
#pragma unroll
  for (int i = 0; i < 4; i++)
#pragma unroll
    for (int j = 0; j < 4; j++) acc[i][j] = zv;

  for (int kt = 0; kt < ksteps; ++kt) {
    const int k0 = zb * kchunk + kt * 32;
    __syncthreads();
    if (AMODE == 1) {
      const int nd = k0 / 320;
      const int cb = k0 - nd * 320 + skg * 8;
#pragma unroll
      for (int i = 0; i < 2; i++) {
        const int row = i * 64 + srow;
        const long v = sIdx[row * 3 + nd];
        ASYNC_CP16(emb + v * 320 + cb, smem + i * 4096 + t * 16);
      }
    } else {
#pragma unroll
      for (int i = 0; i < 2; i++) {
        const int row = i * 64 + srow;
        ASYNC_CP16(Ab + (long)(m0 + row) * lda + k0 + skg * 8,
                   smem + i * 4096 + t * 16);
      }
    }
#pragma unroll
    for (int i = 0; i < 2; i++) {
      const int row = i * 64 + srow;
      ASYNC_CP16(Bb + (long)(n0 + row) * ldb + k0 + skg * 8,
                 smem + 8192 + i * 4096 + t * 16);
    }
    __syncthreads();
    s16x8 af[4], bv[4];
#pragma unroll
    for (int mi = 0; mi < 4; mi++)
      af[mi] = *(const s16x8*)(sA + (wr * 64 + mi * 16 + fr) * 32 + fq * 8);
#pragma unroll
    for (int ni = 0; ni < 4; ni++)
      bv[ni] = *(const s16x8*)(sB + (wc * 64 + ni * 16 + fr) * 32 + fq * 8);
#pragma unroll
    for (int mi = 0; mi < 4; mi++)
#pragma unroll
      for (int ni = 0; ni < 4; ni++)
        acc[mi][ni] = __builtin_amdgcn_mfma_f32_16x16x32_bf16(
            af[mi], bv[ni], acc[mi][ni], 0, 0, 0);
  }

  if (EPI == 0) {
#pragma unroll
    for (int ni = 0; ni < 4; ni++) {
      const int gn = n0 + wc * 64 + ni * 16 + fr;
      const float bval = bias[gn];
#pragma unroll
      for (int mi = 0; mi < 4; mi++)
#pragma unroll
        for (int j = 0; j < 4; j++) {
          const int gm = m0 + wr * 64 + mi * 16 + fq * 4 + j;
          Cbf[(long)gm * ldc + gn] = f2bfr(acc[mi][ni][j] + bval);
        }
    }
  } else if (EPI == 1) {
#pragma unroll
    for (int mi = 0; mi < 4; mi++)
#pragma unroll
      for (int ni = 0; ni < 4; ni++) {
        const int nt = wc * 64 + ni * 16 + fr;
#pragma unroll
        for (int j = 0; j < 4; j++) {
          const int m = wr * 64 + mi * 16 + fq * 4 + j;
          const float hv =
              bfr2f(hqp[(long)zb * strideHq + (long)(m & 15) * 1024 + n0 + nt]);
          sTile[m * 128 + nt] = acc[mi][ni][j] * hv;
        }
      }
    __syncthreads();
    for (int o = t; o < 1024; o += 256) {
      const int h = o >> 7, nn = o & 127;
      float s = 0.f;
#pragma unroll
      for (int q = 0; q < 16; q++) s += sTile[(h * 16 + q) * 128 + nn];
      pooled[(long)zb * 8192 + h * 1024 + n0 + nn] = f2bfr(s);
    }
  } else {
#pragma unroll
    for (int ni = 0; ni < 4; ni++) {
      const int gn = n0 + wc * 64 + ni * 16 + fr;
      if (gn < nmax) {
#pragma unroll
        for (int mi = 0; mi < 4; mi++)
#pragma unroll
          for (int j = 0; j < 4; j++) {
            const int gm = m0 + wr * 64 + mi * 16 + fq * 4 + j;
            Cf[(long)zb * strideCf + (long)gm * ldcf + gn] = acc[mi][ni][j];
          }
      }
    }
  }
}

// ---------------- hs transpose: [b*256+s][c] -> [b][c][s] ----------------
__global__ __launch_bounds__(256) void transpose_hs(const uint16_t* __restrict__ hs,
                                                    uint16_t* __restrict__ hsT) {
  __shared__ uint16_t tile[64][68];
  const int b = blockIdx.z, s0 = blockIdx.y * 64, c0 = blockIdx.x * 64;
  const int t = threadIdx.x;
#pragma unroll
  for (int i = 0; i < 4; i++) {
    const int v = t + i * 256;
    const int r = v >> 4, c4 = (v & 15) * 4;
    ushort4 u = *(const ushort4*)(hs + (long)(b * 256 + s0 + r) * 1024 + c0 + c4);
    tile[r][c4] = u.x; tile[r][c4 + 1] = u.y; tile[r][c4 + 2] = u.z; tile[r][c4 + 3] = u.w;
  }
  __syncthreads();
#pragma unroll
  for (int i = 0; i < 4; i++) {
    const int v = t + i * 256;
    const int rc = v >> 4, s4 = (v & 15) * 4;
    ushort4 u;
    u.x = tile[s4][rc]; u.y = tile[s4 + 1][rc]; u.z = tile[s4 + 2][rc]; u.w = tile[s4 + 3][rc];
    *(ushort4*)(hsT + ((long)b * 1024 + c0 + rc) * 256 + s0 + s4) = u;
  }
}

// ---------------- logits + per-(b,h) softmax -> att (bf16) ----------------
// block = one b.  D[m=h*16+q][s] = sum_c (hq[q,c]*W[h,c]) * hs[s,c]
__global__ __launch_bounds__(256) void logits_softmax(
    const uint16_t* __restrict__ hq, const uint16_t* __restrict__ watt,
    const uint16_t* __restrict__ hs, uint16_t* __restrict__ att) {
  __shared__ uint16_t sHq[16 * 32];
  __shared__ uint16_t sW[8 * 32];
  __shared__ uint16_t sB[256 * 32];
  __shared__ float sStat[8 * 128];
  __shared__ float sHmax[8];
  __shared__ float sHsum[8];

  const int b = blockIdx.x;
  const int t = threadIdx.x, lane = t & 63, wave = t >> 6;
  const int wr = wave >> 1, wc = wave & 1;
  const int fr = lane & 15, fq = lane >> 4;
  const int srow = t >> 2, skg = t & 3;

  f32x4 zv = {0.f, 0.f, 0.f, 0.f};
  f32x4 acc[4][8];
#pragma unroll
  for (int i = 0; i < 4; i++)
#pragma unroll
    for (int j = 0; j < 8; j++) acc[i][j] = zv;

  for (int kt = 0; kt < 32; ++kt) {
    const int k0 = kt * 32;
    __syncthreads();
    {
      const int row = t >> 4, w2 = (t & 15) * 2;
      *(uint32_t*)(sHq + row * 32 + w2) =
          *(const uint32_t*)(hq + (long)(b * 16 + row) * 1024 + k0 + w2);
      if (t < 128)
        *(uint32_t*)(sW + row * 32 + w2) =
            *(const uint32_t*)(watt + (long)row * 1024 + k0 + w2);
    }
#pragma unroll
    for (int i = 0; i < 4; i++) {
      const int row = i * 64 + srow;
      ASYNC_CP16(hs + ((long)b * 256 + row) * 1024 + k0 + skg * 8,
                 (char*)sB + i * 4096 + t * 16);
    }
    __syncthreads();
    s16x8 af[4], bv[8];
#pragma unroll
    for (int mi = 0; mi < 4; mi++) {
      const int h = wr * 4 + mi;
      s16x8 vv;
#pragma unroll
      for (int j = 0; j < 8; j++) {
        const int k = fq * 8 + j;
        vv[j] = (short)f2bfr(bfr2f(sHq[fr * 32 + k]) * bfr2f(sW[h * 32 + k]));
      }
      af[mi] = vv;
    }
#pragma unroll
    for (int ni = 0; ni < 8; ni++)
      bv[ni] = *(const s16x8*)(sB + (wc * 128 + ni * 16 + fr) * 32 + fq * 8);
#pragma unroll
    for (int mi = 0; mi < 4; mi++)
#pragma unroll
      for (int ni = 0; ni < 8; ni++)
        acc[mi][ni] = __builtin_amdgcn_mfma_f32_16x16x32_bf16(
            af[mi], bv[ni], acc[mi][ni], 0, 0, 0);
  }

  const int tid2 = wc * 64 + lane;
#pragma unroll
  for (int mi = 0; mi < 4; mi++) {
    float mx = -1e30f;
#pragma unroll
    for (int ni = 0; ni < 8; ni++)
#pragma unroll
      for (int j = 0; j < 4; j++) mx = fmaxf(mx, acc[mi][ni][j]);
    sStat[(wr * 4 + mi) * 128 + tid2] = mx;
  }
  __syncthreads();
  {
    const int h = t >> 5, i = t & 31;
    float v = fmaxf(fmaxf(sStat[h * 128 + i], sStat[h * 128 + i + 32]),
                    fmaxf(sStat[h * 128 + i + 64], sStat[h * 128 + i + 96]));
#pragma unroll
    for (int d = 1; d < 32; d <<= 1) v = fmaxf(v, __shfl_xor(v, d));
    if (i == 0) sHmax[h] = v;
  }
  __syncthreads();
#pragma unroll
  for (int mi = 0; mi < 4; mi++) {
    const float hm = sHmax[wr * 4 + mi];
    float s = 0.f;
#pragma unroll
    for (int ni = 0; ni < 8; ni++)
#pragma unroll
      for (int j = 0; j < 4; j++) s += __expf(acc[mi][ni][j] - hm);
    sStat[(wr * 4 + mi) * 128 + tid2] = s;
  }
  __syncthreads();
  {
    const int h = t >> 5, i = t & 31;
    float v = sStat[h * 128 + i] + sStat[h * 128 + i + 32] +
              sStat[h * 128 + i + 64] + sStat[h * 128 + i + 96];
#pragma unroll
    for (int d = 1; d < 32; d <<= 1) v += __shfl_xor(v, d);
    if (i == 0) sHsum[h] = v;
  }
  __syncthreads();
#pragma unroll
  for (int mi = 0; mi < 4; mi++) {
    const int h = wr * 4 + mi;
    const float hm = sHmax[h];
    const float ri = 1.f / sHsum[h];
#pragma unroll
    for (int ni = 0; ni < 8; ni++)
#pragma unroll
      for (int j = 0; j < 4; j++) {
        const int m = wr * 64 + mi * 16 + fq * 4 + j;
        const int n = wc * 128 + ni * 16 + fr;
        att[(long)b * 32768 + m * 256 + n] = f2bfr(__expf(acc[mi][ni][j] - hm) * ri);
      }
  }
}

// ---------------- fc partial-sum + bias -> bf16 padded [128][320] ----------------
__global__ __launch_bounds__(256) void cvt_out_k(const float* __restrict__ parts,
                                                 const float* __restrict__ fc_b,
                                                 uint16_t* __restrict__ outb) {
  int idx = blockIdx.x * 256 + threadIdx.x;
  if (idx >= 128 * 320) return;
  int m = idx / 320, n = idx % 320;
  float v = 0.f;
  if (n < 300) {
    v = fc_b[n];
#pragma unroll
    for (int ch = 0; ch < 8; ch++) v += parts[ch * 38400 + m * 300 + n];
  }
  outb[idx] = f2bfr(v);
}

// ---------------- row log-softmax over 5000 ----------------
__global__ __launch_bounds__(256) void logsoftmax_k(const float* __restrict__ sim,
                                                    float* __restrict__ out) {
  const int r = blockIdx.x, t = threadIdx.x;
  __shared__ float red[4];
  __shared__ float red2[4];
  const float* x = sim + (long)r * 5000;
  float mx = -1e30f;
  for (int i = t; i < 5000; i += 256) mx = fmaxf(mx, x[i]);
#pragma unroll
  for (int d = 1; d < 64; d <<= 1) mx = fmaxf(mx, __shfl_xor(mx, d));
  if ((t & 63) == 0) red[t >> 6] = mx;
  __syncthreads();
  mx = fmaxf(fmaxf(red[0], red[1]), fmaxf(red[2], red[3]));
  float s = 0.f;
  for (int i = t; i < 5000; i += 256) s += __expf(x[i] - mx);
#pragma unroll
  for (int d = 1; d < 64; d <<= 1) s += __shfl_xor(s, d);
  if ((t & 63) == 0) red2[t >> 6] = s;
  __syncthreads();
  s = red2[0] + red2[1] + red2[2] + red2[3];
  const float lse = mx + logf(s);
  float* o = out + (long)r * 5000;
  for (int i = t; i < 5000; i += 256) o[i] = x[i] - lse;
}

// ---------------------------------------------------------------------------
extern "C" void kernel_launch(void* const* d_in, const int* in_sizes, int n_in,
                              void* d_out, int out_size, void* d_ws, size_t ws_size,
                              hipStream_t stream) {
  (void)in_sizes; (void)n_in; (void)out_size; (void)ws_size;
  const int* he_q = (const int*)d_in[0];
  const int* he_k = (const int*)d_in[1];
  const float* emb_f = (const float*)d_in[2];
  const float* q2h_w = (const float*)d_in[3];
  const float* q2h_b = (const float*)d_in[4];
  const float* k2h_w = (const float*)d_in[5];
  const float* k2h_b = (const float*)d_in[6];
  const float* h2att_w = (const float*)d_in[7];
  // d_in[8] = h2att_b: uniform per-head shift, softmax-invariant -> unused
  const float* fc_w = (const float*)d_in[9];
  const float* fc_b = (const float*)d_in[10];
  const float* glove = (const float*)d_in[11];
  float* out = (float*)d_out;

  char* ws = (char*)d_ws;
  uint16_t* EMB   = (uint16_t*)(ws);              // 50000x320 bf16   32,000,000
  uint16_t* WK    = (uint16_t*)(ws + 32000000);   // 1024x960         1,966,080
  uint16_t* WQ    = (uint16_t*)(ws + 33966080);   // 1024x960         1,966,080
  uint16_t* WATT  = (uint16_t*)(ws + 35932160);   // 8x1024              16,384
  uint16_t* WFC   = (uint16_t*)(ws + 35948544);   // 384x8192         6,291,456
  uint16_t* GLV   = (uint16_t*)(ws + 42240000);   // 5120x320         3,276,800
  uint16_t* HQ    = (uint16_t*)(ws + 45516800);   // 2048x1024        4,194,304
  uint16_t* HS    = (uint16_t*)(ws + 49711104);   // 32768x1024      67,108,864
  uint16_t* HST   = (uint16_t*)(ws + 116819968);  // 128x1024x256    67,108,864
  uint16_t* ATT   = (uint16_t*)(ws + 183928832);  // 128x128x256      8,388,608
  uint16_t* POOL  = (uint16_t*)(ws + 192317440);  // 128x8192         2,097,152
  float*    PARTS = (float*)(ws + 194414592);     // 8x128x300 f32    1,228,800
  uint16_t* OUTB  = (uint16_t*)(ws + 195643392);  // 128x320             81,920
  float*    SIM   = (float*)(ws + 195725312);     // 128x5000 f32     2,560,000
  // total ~189.1 MB

  // 1) conversions
  cvt_pad300<<<15625, 256, 0, stream>>>(emb_f, EMB, 50000, 50000);
  cvt_pad300<<<960, 256, 0, stream>>>(k2h_w, WK, 3072, 3072);
  cvt_pad300<<<960, 256, 0, stream>>>(q2h_w, WQ, 3072, 3072);
  cvt_pad300<<<1600, 256, 0, stream>>>(glove, GLV, 5120, 5000);
  cvt_plain<<<32, 256, 0, stream>>>(h2att_w, WATT, 8192);
  cvt_fc<<<3072, 256, 0, stream>>>(fc_w, WFC);

  // 2) projections (gather fused into A staging)
  gemm_bt128<1, 0><<<dim3(8, 256, 1), 256, 17920, stream>>>(
      nullptr, 0, 0, he_k, EMB, WK, 960, 0, 30, 0, k2h_b, HS, 1024,
      nullptr, 0, 0, 0, nullptr, 0, nullptr);
  gemm_bt128<1, 0><<<dim3(8, 16, 1), 256, 17920, stream>>>(
      nullptr, 0, 0, he_q, EMB, WQ, 960, 0, 30, 0, q2h_b, HQ, 1024,
      nullptr, 0, 0, 0, nullptr, 0, nullptr);

  // 3) transpose
  transpose_hs<<<dim3(16, 4, 128), 256, 0, stream>>>(HS, HST);

  // 4) logits + softmax
  logits_softmax<<<128, 256, 0, stream>>>(HQ, WATT, HS, ATT);

  // 5) t = att@hs, pooled fused
  gemm_bt128<0, 1><<<dim3(8, 1, 128), 256, 81920, stream>>>(
      ATT, 256, 32768, nullptr, nullptr, HST, 256, 262144, 8, 0, nullptr,
      nullptr, 0, nullptr, 0, 0, 0, HQ, 16384, POOL);

  // 6) fc split-K (8 chunks of 1024)
  gemm_bt128<0, 2><<<dim3(3, 1, 8), 256, 16384, stream>>>(
      POOL, 8192, 0, nullptr, nullptr, WFC, 8192, 0, 32, 1024, nullptr,
      nullptr, 0, PARTS, 300, 300, 38400, nullptr, 0, nullptr);

  // 7) sum partials + fc_b -> bf16 padded
  cvt_out_k<<<160, 256, 0, stream>>>(PARTS, fc_b, OUTB);

  // 8) sim = out @ glove^T
  gemm_bt128<0, 2><<<dim3(40, 1, 1), 256, 16384, stream>>>(
      OUTB, 320, 0, nullptr, nullptr, GLV, 320, 0, 10, 0, nullptr,
      nullptr, 0, SIM, 5000, 5000, 0, nullptr, 0, nullptr);

  // 9) log-softmax
  logsoftmax_k<<<128, 256, 0, stream>>>(SIM, out);
}

// Round 2
// 270.628 us; speedup vs baseline: 1.1483x; 1.1483x over previous
//
#include <hip/hip_runtime.h>
#include <stdint.h>

// ---------------------------------------------------------------------------
// HAN forward on MI355X (gfx950).  Pipeline (R2):
//  1) convert emb/weights to bf16 (emb padded per-node 300->320, KPAD=960)
//  2) hs = gather(emb,he_kg)@Wk^T + bk   (MFMA GEMM, gather offsets hoisted,
//     XCD-chunked swizzle so the 8 n-tiles sharing A co-reside on one XCD)
//     hq = gather(emb,he_q )@Wq^T + bq
//  3) hsT[b][c][s] transpose (LDS-tiled)
//  4) A2[b][h*16+q][c] = bf16(hq*W_h)  (elementwise)
//     logits = A2 @ hs^T (batched MFMA GEMM, bf16 -> ATT buffer)
//     softmax in-place per (b,h)  (h2att_b dropped: softmax-invariant)
//  5) t = att@hs (via hsT); pooled[b,h,c] = sum_q hq[q,c]*t[h,q,c] fused via
//     shfl-reduce epilogue
//  6) fc split-K partials; 7) +fc_b -> bf16; 8) sim = out@glove^T; 9) logsoftmax
// ---------------------------------------------------------------------------

typedef short s16x8 __attribute__((ext_vector_type(8)));
typedef float f32x4 __attribute__((ext_vector_type(4)));

#define ASYNC_CP16(gsrc, ldst)                                                  \
  __builtin_amdgcn_global_load_lds(                                             \
      (const __attribute__((address_space(1))) void*)(gsrc),                    \
      (__attribute__((address_space(3))) void*)(ldst), 16, 0, 0)

__device__ __forceinline__ float bfr2f(uint16_t u) {
  return __builtin_bit_cast(float, (uint32_t)u << 16);
}
__device__ __forceinline__ uint16_t f2bfr(float f) {
  uint32_t u = __builtin_bit_cast(uint32_t, f);
  u += 0x7fffu + ((u >> 16) & 1u);   // RNE
  return (uint16_t)(u >> 16);
}

// ---------------- conversion kernels ----------------

__global__ __launch_bounds__(256) void cvt_pad300(const float* __restrict__ src,
                                                  uint16_t* __restrict__ dst,
                                                  int rows_out, int rows_src) {
  int idx = blockIdx.x * 256 + threadIdx.x;
  if (idx >= rows_out * 80) return;
  int r = idx / 80, j = idx % 80;
  float4 v = make_float4(0.f, 0.f, 0.f, 0.f);
  if (r < rows_src && j < 75) v = *(const float4*)(src + (size_t)r * 300 + j * 4);
  ushort4 o;
  o.x = f2bfr(v.x); o.y = f2bfr(v.y); o.z = f2bfr(v.z); o.w = f2bfr(v.w);
  *(ushort4*)(dst + (size_t)r * 320 + j * 4) = o;
}

__global__ __launch_bounds__(256) void cvt_plain(const float* __restrict__ src,
                                                 uint16_t* __restrict__ dst, int n) {
  int i = blockIdx.x * 256 + threadIdx.x;
  if (i < n) dst[i] = f2bfr(src[i]);
}

// fc_w [300][8192] f32 -> [384][8192] bf16 (rows >=300 zero)
__global__ __launch_bounds__(256) void cvt_fc(const float* __restrict__ src,
                                              uint16_t* __restrict__ dst) {
  int i4 = blockIdx.x * 256 + threadIdx.x;  // < 384*2048
  int pos = i4 * 4;
  int r = pos >> 13, c = pos & 8191;
  float4 v = make_float4(0.f, 0.f, 0.f, 0.f);
  if (r < 300) v = *(const float4*)(src + (size_t)r * 8192 + c);
  ushort4 o;
  o.x = f2bfr(v.x); o.y = f2bfr(v.y); o.z = f2bfr(v.z); o.w = f2bfr(v.w);
  *(ushort4*)(dst + (size_t)r * 8192 + c) = o;
}

// ---------------- gather-GEMM: C[128m][1024] = gather(emb,he)@W^T + b -------
// K = 960 fixed (3 nodes x 320), BK=32.  XCD-chunked swizzle over (x=n, y=m).
__global__ __launch_bounds__(256) void gemm_gather(
    const int* __restrict__ he, const uint16_t* __restrict__ emb,
    const uint16_t* __restrict__ W, const float* __restrict__ bias,
    uint16_t* __restrict__ C) {
  __shared__ uint16_t sA[4096];
  __shared__ uint16_t sB[4096];
  __shared__ int sIdx[384];

  const int t = threadIdx.x;
  const int lane = t & 63, wave = t >> 6;
  const int wr = wave >> 1, wc = wave & 1;
  const int fr = lane & 15, fq = lane >> 4;
  const int srow = t >> 2, skg = t & 3;

  // bijective XCD-chunk swizzle (nwg % 8 == 0 for all our grids)
  const int nwg = gridDim.x * gridDim.y;
  const int v = blockIdx.x + gridDim.x * blockIdx.y;
  const int w = (v & 7) * (nwg >> 3) + (v >> 3);
  const int bx = w % gridDim.x;
  const int by = w / gridDim.x;
  const int m0 = by * 128, n0 = bx * 128;

  for (int i = t; i < 384; i += 256) sIdx[i] = he[(long)m0 * 3 + i];
  __syncthreads();

  uint32_t eoff[2][3];
#pragma unroll
  for (int i = 0; i < 2; i++) {
    const int row = i * 64 + srow;
#pragma unroll
    for (int nd = 0; nd < 3; nd++)
      eoff[i][nd] = (uint32_t)sIdx[row * 3 + nd] * 640u + (uint32_t)(skg * 16);
  }
  const uint16_t* Bp0 = W + (long)(n0 + srow) * 960 + skg * 8;
  const uint16_t* Bp1 = W + (long)(n0 + 64 + srow) * 960 + skg * 8;

  f32x4 zv = {0.f, 0.f, 0.f, 0.f};
  f32x4 acc[4][4];
#pragma unroll
  for (int i = 0; i < 4; i++)
#pragma unroll
    for (int j = 0; j < 4; j++) acc[i][j] = zv;

#pragma unroll
  for (int nd = 0; nd < 3; nd++) {
#pragma unroll
    for (int kk = 0; kk < 10; kk++) {
      const int kof = nd * 320 + kk * 32;
      __syncthreads();
      ASYNC_CP16((const char*)emb + eoff[0][nd] + kk * 64, (char*)sA + t * 16);
      ASYNC_CP16((const char*)emb + eoff[1][nd] + kk * 64,
                 (char*)sA + 4096 + t * 16);
      ASYNC_CP16(Bp0 + kof, (char*)sB + t * 16);
      ASYNC_CP16(Bp1 + kof, (char*)sB + 4096 + t * 16);
      __syncthreads();
      s16x8 af[4], bv[4];
#pragma unroll
      for (int mi = 0; mi < 4; mi++)
        af[mi] = *(const s16x8*)(sA + (wr * 64 + mi * 16 + fr) * 32 + fq * 8);
#pragma unroll
      for (int ni = 0; ni < 4; ni++)
        bv[ni] = *(const s16x8*)(sB + (wc * 64 + ni * 16 + fr) * 32 + fq * 8);
#pragma unroll
      for (int mi = 0; mi < 4; mi++)
#pragma unroll
        for (int ni = 0; ni < 4; ni++)
          acc[mi][ni] = __builtin_amdgcn_mfma_f32_16x16x32_bf16(
              af[mi], bv[ni], acc[mi][ni], 0, 0, 0);
    }
  }

#pragma unroll
  for (int ni = 0; ni < 4; ni++) {
    const int gn = n0 + wc * 64 + ni * 16 + fr;
    const float bval = bias[gn];
#pragma unroll
    for (int mi = 0; mi < 4; mi++)
#pragma unroll
      for (int j = 0; j < 4; j++) {
        const int gm = m0 + wr * 64 + mi * 16 + fq * 4 + j;
        C[(long)gm * 1024 + gn] = f2bfr(acc[mi][ni][j] + bval);
      }
  }
}

// ---------------- generic 128x128 bf16 MFMA GEMM, C = A @ Bt^T --------------
// EPI: 1 = pooled shfl-reduce epilogue; 2 = f32 store (col guard); 3 = bf16
// SWZ: 1 = XCD-chunk swizzle over (x, z)
template <int EPI, int SWZ>
__global__ __launch_bounds__(256) void gemm_plain(
    const uint16_t* __restrict__ A, int lda, long sAb,
    const uint16_t* __restrict__ Bt, int ldb, long sBb,
    int ksteps, int kchunk,
    uint16_t* __restrict__ Cbf, int ldc, long sCbf,
    float* __restrict__ Cf, int ldcf, int nmax, long sCf,
    const uint16_t* __restrict__ hqp, uint16_t* __restrict__ pooled) {
  __shared__ uint16_t sA[4096];
  __shared__ uint16_t sB[4096];
  __shared__ uint16_t sHq[2048];

  const int t = threadIdx.x;
  const int lane = t & 63, wave = t >> 6;
  const int wr = wave >> 1, wc = wave & 1;
  const int fr = lane & 15, fq = lane >> 4;
  const int srow = t >> 2, skg = t & 3;

  int bx = blockIdx.x, bz = blockIdx.z;
  if (SWZ) {
    const int nwg = gridDim.x * gridDim.z;
    const int v = bx + gridDim.x * bz;
    const int w = (v & 7) * (nwg >> 3) + (v >> 3);
    bx = w % gridDim.x;
    bz = w / gridDim.x;
  }
  const int m0 = blockIdx.y * 128, n0 = bx * 128;
  const uint16_t* Ab = A + (long)bz * sAb;
  const uint16_t* Bb = Bt + (long)bz * sBb;

  if (EPI == 1) {
    const int q = t >> 4, c8 = (t & 15) * 8;
    *(s16x8*)(sHq + q * 128 + c8) =
        *(const s16x8*)(hqp + (long)bz * 16384 + (long)q * 1024 + n0 + c8);
  }

  f32x4 zv = {0.f, 0.f, 0.f, 0.f};
  f32x4 acc[4][4];
#pragma unroll
  for (int i = 0; i < 4; i++)
#pragma unroll
    for (int j = 0; j < 4; j++) acc[i][j] = zv;

  const uint16_t* Ap0 = Ab + (long)(m0 + srow) * lda + skg * 8;
  const uint16_t* Ap1 = Ab + (long)(m0 + 64 + srow) * lda + skg * 8;
  const uint16_t* Bq0 = Bb + (long)(n0 + srow) * ldb + skg * 8;
  const uint16_t* Bq1 = Bb + (long)(n0 + 64 + srow) * ldb + skg * 8;

  for (int kt = 0; kt < ksteps; ++kt) {
    const int k0 = bz * kchunk + kt * 32;
    __syncthreads();
    ASYNC_CP16(Ap0 + k0, (char*)sA + t * 16);
    ASYNC_CP16(Ap1 + k0, (char*)sA + 4096 + t * 16);
    ASYNC_CP16(Bq0 + k0, (char*)sB + t * 16);
    ASYNC_CP16(Bq1 + k0, (char*)sB + 4096 + t * 16);
    __syncthreads();
    s16x8 af[4], bv[4];
#pragma unroll
    for (int mi = 0; mi < 4; mi++)
      af[mi] = *(const s16x8*)(sA + (wr * 64 + mi * 16 + fr) * 32 + fq * 8);
#pragma unroll
    for (int ni = 0; ni < 4; ni++)
      bv[ni] = *(const s16x8*)(sB + (wc * 64 + ni * 16 + fr) * 32 + fq * 8);
#pragma unroll
    for (int mi = 0; mi < 4; mi++)
#pragma unroll
      for (int ni = 0; ni < 4; ni++)
        acc[mi][ni] = __builtin_amdgcn_mfma_f32_16x16x32_bf16(
            af[mi], bv[ni], acc[mi][ni], 0, 0, 0);
  }

  if (EPI == 1) {
#pragma unroll
    for (int mi = 0; mi < 4; mi++) {
      const int hh = wr * 4 + mi;
#pragma unroll
      for (int ni = 0; ni < 4; ni++) {
        const int col = wc * 64 + ni * 16 + fr;
        float p = 0.f;
#pragma unroll
        for (int j = 0; j < 4; j++)
          p += acc[mi][ni][j] * bfr2f(sHq[(fq * 4 + j) * 128 + col]);
        p += __shfl_xor(p, 16);
        p += __shfl_xor(p, 32);
        if (fq == 0)
          pooled[(long)bz * 8192 + hh * 1024 + n0 + col] = f2bfr(p);
      }
    }
  } else if (EPI == 2) {
#pragma unroll
    for (int ni = 0; ni < 4; ni++) {
      const int gn = n0 + wc * 64 + ni * 16 + fr;
      if (gn < nmax) {
#pragma unroll
        for (int mi = 0; mi < 4; mi++)
#pragma unroll
          for (int j = 0; j < 4; j++) {
            const int gm = m0 + wr * 64 + mi * 16 + fq * 4 + j;
            Cf[(long)bz * sCf + (long)gm * ldcf + gn] = acc[mi][ni][j];
          }
      }
    }
  } else {
#pragma unroll
    for (int ni = 0; ni < 4; ni++) {
      const int gn = n0 + wc * 64 + ni * 16 + fr;
#pragma unroll
      for (int mi = 0; mi < 4; mi++)
#pragma unroll
        for (int j = 0; j < 4; j++) {
          const int gm = m0 + wr * 64 + mi * 16 + fq * 4 + j;
          Cbf[(long)bz * sCbf + (long)gm * ldc + gn] = f2bfr(acc[mi][ni][j]);
        }
    }
  }
}

// ---------------- hs transpose: [b*256+s][c] -> [b][c][s] ----------------
__global__ __launch_bounds__(256) void transpose_hs(const uint16_t* __restrict__ hs,
                                                    uint16_t* __restrict__ hsT) {
  __shared__ uint16_t tile[64][68];
  const int b = blockIdx.z, s0 = blockIdx.y * 64, c0 = blockIdx.x * 64;
  const int t = threadIdx.x;
#pragma unroll
  for (int i = 0; i < 4; i++) {
    const int v = t + i * 256;
    const int r = v >> 4, c4 = (v & 15) * 4;
    ushort4 u = *(const ushort4*)(hs + (long)(b * 256 + s0 + r) * 1024 + c0 + c4);
    tile[r][c4] = u.x; tile[r][c4 + 1] = u.y; tile[r][c4 + 2] = u.z; tile[r][c4 + 3] = u.w;
  }
  __syncthreads();
#pragma unroll
  for (int i = 0; i < 4; i++) {
    const int v = t + i * 256;
    const int rc = v >> 4, s4 = (v & 15) * 4;
    ushort4 u;
    u.x = tile[s4][rc]; u.y = tile[s4 + 1][rc]; u.z = tile[s4 + 2][rc]; u.w = tile[s4 + 3][rc];
    *(ushort4*)(hsT + ((long)b * 1024 + c0 + rc) * 256 + s0 + s4) = u;
  }
}

// ---------------- A2[b][h*16+q][c] = bf16(hq[b,q,c] * W[h,c]) ----------------
__global__ __launch_bounds__(256) void mul_hw(const uint16_t* __restrict__ hq,
                                              const uint16_t* __restrict__ watt,
                                              uint16_t* __restrict__ a2) {
  const int idx = blockIdx.x * 256 + threadIdx.x;  // 128*128*128
  const int b = idx >> 14;
  const int m = (idx >> 7) & 127;
  const int c8 = (idx & 127) * 8;
  const int h = m >> 4, q = m & 15;
  s16x8 hv = *(const s16x8*)(hq + ((long)(b * 16 + q)) * 1024 + c8);
  s16x8 wv = *(const s16x8*)(watt + h * 1024 + c8);
  s16x8 o;
#pragma unroll
  for (int j = 0; j < 8; j++)
    o[j] = (short)f2bfr(bfr2f((uint16_t)hv[j]) * bfr2f((uint16_t)wv[j]));
  *(s16x8*)(a2 + (long)idx * 8) = o;
}

// ---------------- in-place softmax over [b][h]: 16x256 bf16 rows -------------
__global__ __launch_bounds__(256) void softmax_att(uint16_t* __restrict__ att) {
  const int b = blockIdx.x >> 3, h = blockIdx.x & 7;
  uint16_t* base = att + (long)b * 32768 + h * 4096;
  const int t = threadIdx.x;
  __shared__ float red[8];
  s16x8 v0 = *(const s16x8*)(base + t * 16);
  s16x8 v1 = *(const s16x8*)(base + t * 16 + 8);
  float f[16];
#pragma unroll
  for (int j = 0; j < 8; j++) {
    f[j] = bfr2f((uint16_t)v0[j]);
    f[8 + j] = bfr2f((uint16_t)v1[j]);
  }
  float mx = f[0];
#pragma unroll
  for (int j = 1; j < 16; j++) mx = fmaxf(mx, f[j]);
#pragma unroll
  for (int d = 1; d < 64; d <<= 1) mx = fmaxf(mx, __shfl_xor(mx, d));
  if ((t & 63) == 0) red[t >> 6] = mx;
  __syncthreads();
  mx = fmaxf(fmaxf(red[0], red[1]), fmaxf(red[2], red[3]));
  float s = 0.f;
#pragma unroll
  for (int j = 0; j < 16; j++) {
    f[j] = __expf(f[j] - mx);
    s += f[j];
  }
#pragma unroll
  for (int d = 1; d < 64; d <<= 1) s += __shfl_xor(s, d);
  if ((t & 63) == 0) red[4 + (t >> 6)] = s;
  __syncthreads();
  const float ri = 1.f / (red[4] + red[5] + red[6] + red[7]);
  s16x8 o0, o1;
#pragma unroll
  for (int j = 0; j < 8; j++) {
    o0[j] = (short)f2bfr(f[j] * ri);
    o1[j] = (short)f2bfr(f[8 + j] * ri);
  }
  *(s16x8*)(base + t * 16) = o0;
  *(s16x8*)(base + t * 16 + 8) = o1;
}

// ---------------- fc partial-sum + bias -> bf16 padded [128][320] ------------
__global__ __launch_bounds__(256) void cvt_out_k(const float* __restrict__ parts,
                                                 const float* __restrict__ fc_b,
                                                 uint16_t* __restrict__ outb) {
  int idx = blockIdx.x * 256 + threadIdx.x;
  if (idx >= 128 * 320) return;
  int m = idx / 320, n = idx % 320;
  float v = 0.f;
  if (n < 300) {
    v = fc_b[n];
#pragma unroll
    for (int ch = 0; ch < 8; ch++) v += parts[ch * 38400 + m * 300 + n];
  }
  outb[idx] = f2bfr(v);
}

// ---------------- row log-softmax over 5000 ----------------
__global__ __launch_bounds__(256) void logsoftmax_k(const float* __restrict__ sim,
                                                    float* __restrict__ out) {
  const int r = blockIdx.x, t = threadIdx.x;
  __shared__ float red[4];
  __shared__ float red2[4];
  const float* x = sim + (long)r * 5000;
  float mx = -1e30f;
  for (int i = t; i < 5000; i += 256) mx = fmaxf(mx, x[i]);
#pragma unroll
  for (int d = 1; d < 64; d <<= 1) mx = fmaxf(mx, __shfl_xor(mx, d));
  if ((t & 63) == 0) red[t >> 6] = mx;
  __syncthreads();
  mx = fmaxf(fmaxf(red[0], red[1]), fmaxf(red[2], red[3]));
  float s = 0.f;
  for (int i = t; i < 5000; i += 256) s += __expf(x[i] - mx);
#pragma unroll
  for (int d = 1; d < 64; d <<= 1) s += __shfl_xor(s, d);
  if ((t & 63) == 0) red2[t >> 6] = s;
  __syncthreads();
  s = red2[0] + red2[1] + red2[2] + red2[3];
  const float lse = mx + logf(s);
  float* o = out + (long)r * 5000;
  for (int i = t; i < 5000; i += 256) o[i] = x[i] - lse;
}

// ---------------------------------------------------------------------------
extern "C" void kernel_launch(void* const* d_in, const int* in_sizes, int n_in,
                              void* d_out, int out_size, void* d_ws, size_t ws_size,
                              hipStream_t stream) {
  (void)in_sizes; (void)n_in; (void)out_size; (void)ws_size;
  const int* he_q = (const int*)d_in[0];
  const int* he_k = (const int*)d_in[1];
  const float* emb_f = (const float*)d_in[2];
  const float* q2h_w = (const float*)d_in[3];
  const float* q2h_b = (const float*)d_in[4];
  const float* k2h_w = (const float*)d_in[5];
  const float* k2h_b = (const float*)d_in[6];
  const float* h2att_w = (const float*)d_in[7];
  // d_in[8] = h2att_b: uniform per-head shift, softmax-invariant -> unused
  const float* fc_w = (const float*)d_in[9];
  const float* fc_b = (const float*)d_in[10];
  const float* glove = (const float*)d_in[11];
  float* out = (float*)d_out;

  char* ws = (char*)d_ws;
  uint16_t* EMB   = (uint16_t*)(ws);              // 50000x320 bf16   32,000,000
  uint16_t* WK    = (uint16_t*)(ws + 32000000);   // 1024x960         1,966,080
  uint16_t* WQ    = (uint16_t*)(ws + 33966080);   // 1024x960         1,966,080
  uint16_t* WATT  = (uint16_t*)(ws + 35932160);   // 8x1024              16,384
  uint16_t* WFC   = (uint16_t*)(ws + 35948544);   // 384x8192         6,291,456
  uint16_t* GLV   = (uint16_t*)(ws + 42240000);   // 5120x320         3,276,800
  uint16_t* HQ    = (uint16_t*)(ws + 45516800);   // 2048x1024        4,194,304
  uint16_t* HS    = (uint16_t*)(ws + 49711104);   // 32768x1024      67,108,864
  uint16_t* HST   = (uint16_t*)(ws + 116819968);  // 128x1024x256    67,108,864
  uint16_t* ATT   = (uint16_t*)(ws + 183928832);  // 128x128x256      8,388,608
  uint16_t* POOL  = (uint16_t*)(ws + 192317440);  // 128x8192         2,097,152
  float*    PARTS = (float*)(ws + 194414592);     // 8x128x300 f32    1,228,800
  uint16_t* OUTB  = (uint16_t*)(ws + 195643392);  // 128x320             81,920
  float*    SIM   = (float*)(ws + 195725312);     // 128x5000 f32     2,560,000
  // A2 aliases the dead EMB+WK region (both dead after the projections):
  uint16_t* A2    = (uint16_t*)(ws);              // 128x128x1024    33,554,432

  // 1) conversions
  cvt_pad300<<<15625, 256, 0, stream>>>(emb_f, EMB, 50000, 50000);
  cvt_pad300<<<960, 256, 0, stream>>>(k2h_w, WK, 3072, 3072);
  cvt_pad300<<<960, 256, 0, stream>>>(q2h_w, WQ, 3072, 3072);
  cvt_pad300<<<1600, 256, 0, stream>>>(glove, GLV, 5120, 5000);
  cvt_plain<<<32, 256, 0, stream>>>(h2att_w, WATT, 8192);
  cvt_fc<<<3072, 256, 0, stream>>>(fc_w, WFC);

  // 2) projections (gather fused into A staging, XCD swizzle)
  gemm_gather<<<dim3(8, 256), 256, 0, stream>>>(he_k, EMB, WK, k2h_b, HS);
  gemm_gather<<<dim3(8, 16), 256, 0, stream>>>(he_q, EMB, WQ, q2h_b, HQ);

  // 3) transpose
  transpose_hs<<<dim3(16, 4, 128), 256, 0, stream>>>(HS, HST);

  // 4) A2, logits (bf16 into ATT), softmax in-place
  mul_hw<<<8192, 256, 0, stream>>>(HQ, WATT, A2);
  gemm_plain<3, 1><<<dim3(2, 1, 128), 256, 0, stream>>>(
      A2, 1024, 131072, HS, 1024, 262144, 32, 0,
      ATT, 256, 32768, nullptr, 0, 0, 0, nullptr, nullptr);
  softmax_att<<<1024, 256, 0, stream>>>(ATT);

  // 5) t = att@hs with fused pooled reduce
  gemm_plain<1, 1><<<dim3(8, 1, 128), 256, 0, stream>>>(
      ATT, 256, 32768, HST, 256, 262144, 8, 0,
      nullptr, 0, 0, nullptr, 0, 0, 0, HQ, POOL);

  // 6) fc split-K (8 chunks of 1024)
  gemm_plain<2, 0><<<dim3(3, 1, 8), 256, 0, stream>>>(
      POOL, 8192, 0, WFC, 8192, 0, 32, 1024,
      nullptr, 0, 0, PARTS, 300, 300, 38400, nullptr, nullptr);

  // 7) sum partials + fc_b -> bf16 padded
  cvt_out_k<<<160, 256, 0, stream>>>(PARTS, fc_b, OUTB);

  // 8) sim = out @ glove^T
  gemm_plain<2, 0><<<dim3(40, 1, 1), 256, 0, stream>>>(
      OUTB, 320, 0, GLV, 320, 0, 10, 0,
      nullptr, 0, 0, SIM, 5000, 5000, 0, nullptr, nullptr);

  // 9) log-softmax
  logsoftmax_k<<<128, 256, 0, stream>>>(SIM, out);
}

// Round 3
// 240.965 us; speedup vs baseline: 1.2897x; 1.1231x over previous
//
#include <hip/hip_runtime.h>
#include <stdint.h>

// ---------------------------------------------------------------------------
// HAN forward on MI355X (gfx950).  R3: counted-vmcnt ring-pipelined MFMA
// GEMMs (3-buffer LDS ring, raw s_barrier, loads in flight across 2 K-steps),
// XOR-swizzled LDS (linear gload_lds dest + pre-swizzled global source +
// swizzled fragment reads), hq merged into hs launch, hsT fused into the
// projection epilogue (transpose kernel eliminated).
// ---------------------------------------------------------------------------

typedef short s16x8 __attribute__((ext_vector_type(8)));
typedef float f32x4 __attribute__((ext_vector_type(4)));

#define ASYNC_CP16(gsrc, ldst)                                                  \
  __builtin_amdgcn_global_load_lds(                                             \
      (const __attribute__((address_space(1))) void*)(gsrc),                    \
      (__attribute__((address_space(3))) void*)(ldst), 16, 0, 0)

__device__ __forceinline__ float bfr2f(uint16_t u) {
  return __builtin_bit_cast(float, (uint32_t)u << 16);
}
__device__ __forceinline__ uint16_t f2bfr(float f) {
  uint32_t u = __builtin_bit_cast(uint32_t, f);
  u += 0x7fffu + ((u >> 16) & 1u);   // RNE
  return (uint16_t)(u >> 16);
}

// ---------------- conversion kernels ----------------

__global__ __launch_bounds__(256) void cvt_pad300(const float* __restrict__ src,
                                                  uint16_t* __restrict__ dst,
                                                  int rows_out, int rows_src) {
  int idx = blockIdx.x * 256 + threadIdx.x;
  if (idx >= rows_out * 80) return;
  int r = idx / 80, j = idx % 80;
  float4 v = make_float4(0.f, 0.f, 0.f, 0.f);
  if (r < rows_src && j < 75) v = *(const float4*)(src + (size_t)r * 300 + j * 4);
  ushort4 o;
  o.x = f2bfr(v.x); o.y = f2bfr(v.y); o.z = f2bfr(v.z); o.w = f2bfr(v.w);
  *(ushort4*)(dst + (size_t)r * 320 + j * 4) = o;
}

__global__ __launch_bounds__(256) void cvt_plain(const float* __restrict__ src,
                                                 uint16_t* __restrict__ dst, int n) {
  int i = blockIdx.x * 256 + threadIdx.x;
  if (i < n) dst[i] = f2bfr(src[i]);
}

// fc_w [300][8192] f32 -> [384][8192] bf16 (rows >=300 zero)
__global__ __launch_bounds__(256) void cvt_fc(const float* __restrict__ src,
                                              uint16_t* __restrict__ dst) {
  int i4 = blockIdx.x * 256 + threadIdx.x;  // < 384*2048
  int pos = i4 * 4;
  int r = pos >> 13, c = pos & 8191;
  float4 v = make_float4(0.f, 0.f, 0.f, 0.f);
  if (r < 300) v = *(const float4*)(src + (size_t)r * 8192 + c);
  ushort4 o;
  o.x = f2bfr(v.x); o.y = f2bfr(v.y); o.z = f2bfr(v.z); o.w = f2bfr(v.w);
  *(ushort4*)(dst + (size_t)r * 8192 + c) = o;
}

// ============ pipelined gather-GEMM: hs (256 m-tiles) + hq (16 m-tiles) =====
// C[128m][1024] = gather(emb,he)@W^T + b,  K=960 (3 nodes x 320), BK=32.
// hs part also writes HST[b][c][s] from registers (fused transpose).
__global__ __launch_bounds__(256) void gemm_gather2(
    const int* __restrict__ heK, const int* __restrict__ heQ,
    const uint16_t* __restrict__ emb,
    const uint16_t* __restrict__ WKp, const uint16_t* __restrict__ WQp,
    const float* __restrict__ bK, const float* __restrict__ bQ,
    uint16_t* __restrict__ HS, uint16_t* __restrict__ HQ,
    uint16_t* __restrict__ HST) {
  __shared__ uint16_t ring[3 * 8192];  // 3 bufs x (A[128][32] + B[128][32])
  __shared__ int sIdx[384];
  char* ringB = (char*)ring;

  const int t = threadIdx.x;
  const int lane = t & 63, wave = t >> 6;
  const int wr = wave >> 1, wc = wave & 1;
  const int fr = lane & 15, fq = lane >> 4;
  const int srow = t >> 2, skg = t & 3;
  const int skg2 = skg ^ ((srow >> 1) & 3);  // inverse LDS swizzle on source

  // bijective XCD-chunk swizzle; grid = (8, 272), nwg = 2176
  const int v = blockIdx.x + 8 * blockIdx.y;
  const int w = (v & 7) * 272 + (v >> 3);
  const int bx = w & 7, by = w >> 3;
  const int n0 = bx * 128;
  const bool isK = by < 256;
  const int m0 = (isK ? by : by - 256) * 128;
  const int* he = isK ? heK : heQ;
  const uint16_t* W = isK ? WKp : WQp;
  const float* bias = isK ? bK : bQ;
  uint16_t* C = isK ? HS : HQ;

  for (int i = t; i < 384; i += 256) sIdx[i] = he[(long)m0 * 3 + i];
  __syncthreads();

  uint32_t ea[2][3];
#pragma unroll
  for (int h = 0; h < 2; h++)
#pragma unroll
    for (int nd = 0; nd < 3; nd++)
      ea[h][nd] =
          (uint32_t)sIdx[(h * 64 + srow) * 3 + nd] * 640u + (uint32_t)(skg2 * 16);
  const uint16_t* Wr0 = W + (long)(n0 + srow) * 960 + skg2 * 8;
  const uint16_t* Wr1 = W + (long)(n0 + 64 + srow) * 960 + skg2 * 8;

  f32x4 zv = {0.f, 0.f, 0.f, 0.f};
  f32x4 acc[4][4];
#pragma unroll
  for (int i = 0; i < 4; i++)
#pragma unroll
    for (int j = 0; j < 4; j++) acc[i][j] = zv;

  int snd = 0, skk = 0, sk = 0, sbuf = 0;
  auto STAGE = [&]() {
    const int bb = sbuf * 16384;
    const uint32_t e0 = snd == 0 ? ea[0][0] : (snd == 1 ? ea[0][1] : ea[0][2]);
    const uint32_t e1 = snd == 0 ? ea[1][0] : (snd == 1 ? ea[1][1] : ea[1][2]);
    ASYNC_CP16((const char*)emb + e0 + skk * 64, ringB + bb + t * 16);
    ASYNC_CP16((const char*)emb + e1 + skk * 64, ringB + bb + 4096 + t * 16);
    ASYNC_CP16(Wr0 + sk, ringB + bb + 8192 + t * 16);
    ASYNC_CP16(Wr1 + sk, ringB + bb + 12288 + t * 16);
    sk += 32;
    if (++skk == 10) { skk = 0; ++snd; }
    if (++sbuf == 3) sbuf = 0;
  };

  STAGE();
  STAGE();

  // lane-constant swizzled fragment offsets (elements)
  const int fsw = (fq ^ ((fr >> 1) & 3)) * 8;
  int aof[4], bof[4];
#pragma unroll
  for (int mi = 0; mi < 4; mi++) aof[mi] = (wr * 64 + mi * 16 + fr) * 32 + fsw;
#pragma unroll
  for (int ni = 0; ni < 4; ni++)
    bof[ni] = 4096 + (wc * 64 + ni * 16 + fr) * 32 + fsw;

  int cbuf = 0;
  for (int kt = 0; kt < 30; ++kt) {
    if (kt < 28) STAGE();
    if (kt < 28)      asm volatile("s_waitcnt vmcnt(8)" ::: "memory");
    else if (kt < 29) asm volatile("s_waitcnt vmcnt(4)" ::: "memory");
    else              asm volatile("s_waitcnt vmcnt(0)" ::: "memory");
    __builtin_amdgcn_s_barrier();
    asm volatile("" ::: "memory");
    const uint16_t* base = ring + cbuf * 8192;
    s16x8 af[4], bv[4];
#pragma unroll
    for (int mi = 0; mi < 4; mi++) af[mi] = *(const s16x8*)(base + aof[mi]);
#pragma unroll
    for (int ni = 0; ni < 4; ni++) bv[ni] = *(const s16x8*)(base + bof[ni]);
#pragma unroll
    for (int mi = 0; mi < 4; mi++)
#pragma unroll
      for (int ni = 0; ni < 4; ni++)
        acc[mi][ni] = __builtin_amdgcn_mfma_f32_16x16x32_bf16(
            af[mi], bv[ni], acc[mi][ni], 0, 0, 0);
    asm volatile("s_waitcnt lgkmcnt(0)" ::: "memory");
    __builtin_amdgcn_s_barrier();
    if (++cbuf == 3) cbuf = 0;
  }

  // epilogue: C (+bias) and, for hs, HST[b][c][s] packed ushort4 stores
#pragma unroll
  for (int ni = 0; ni < 4; ni++) {
    const int gn = n0 + wc * 64 + ni * 16 + fr;
    const float bval = bias[gn];
#pragma unroll
    for (int mi = 0; mi < 4; mi++) {
      const int gmb = m0 + wr * 64 + mi * 16 + fq * 4;
      ushort4 pk;
      uint16_t* cp = C + (long)gmb * 1024 + gn;
      {
        uint16_t b0 = f2bfr(acc[mi][ni][0] + bval);
        uint16_t b1 = f2bfr(acc[mi][ni][1] + bval);
        uint16_t b2 = f2bfr(acc[mi][ni][2] + bval);
        uint16_t b3 = f2bfr(acc[mi][ni][3] + bval);
        cp[0] = b0; cp[1024] = b1; cp[2048] = b2; cp[3072] = b3;
        pk.x = b0; pk.y = b1; pk.z = b2; pk.w = b3;
      }
      if (isK) {
        const int bb = gmb >> 8, sb = gmb & 255;
        *(ushort4*)(HST + ((long)(bb * 1024 + gn)) * 256 + sb) = pk;
      }
    }
  }
}

// ============ pipelined plain GEMM: C = A @ Bt^T ============================
// EPI: 1 = pooled shfl-reduce; 2 = f32 store (col guard); 3 = bf16 store
// SWZ: 1 = XCD-chunk swizzle over (x, z)
template <int EPI, int SWZ>
__global__ __launch_bounds__(256) void gemm_pipe(
    const uint16_t* __restrict__ A, int lda, long sAb,
    const uint16_t* __restrict__ Bt, int ldb, long sBb,
    int ksteps, int kchunk,
    uint16_t* __restrict__ Cbf, int ldc, long sCbf,
    float* __restrict__ Cf, int ldcf, int nmax, long sCf,
    const uint16_t* __restrict__ hqp, uint16_t* __restrict__ pooled) {
  __shared__ uint16_t ring[3 * 8192];
  __shared__ uint16_t sHq[2048];
  char* ringB = (char*)ring;

  const int t = threadIdx.x;
  const int lane = t & 63, wave = t >> 6;
  const int wr = wave >> 1, wc = wave & 1;
  const int fr = lane & 15, fq = lane >> 4;
  const int srow = t >> 2, skg = t & 3;
  const int skg2 = skg ^ ((srow >> 1) & 3);

  int bx = blockIdx.x, bz = blockIdx.z;
  if (SWZ) {
    const int nwg = gridDim.x * gridDim.z;
    const int v = bx + gridDim.x * bz;
    const int w = (v & 7) * (nwg >> 3) + (v >> 3);
    bx = w % gridDim.x;
    bz = w / gridDim.x;
  }
  const int m0 = blockIdx.y * 128, n0 = bx * 128;
  const uint16_t* Ab = A + (long)bz * sAb + (long)bz * 0;
  const uint16_t* Bb = Bt + (long)bz * sBb;

  if (EPI == 1) {
    const int q = t >> 4, c8 = (t & 15) * 8;
    *(s16x8*)(sHq + q * 128 + c8) =
        *(const s16x8*)(hqp + (long)bz * 16384 + (long)q * 1024 + n0 + c8);
  }

  f32x4 zv = {0.f, 0.f, 0.f, 0.f};
  f32x4 acc[4][4];
#pragma unroll
  for (int i = 0; i < 4; i++)
#pragma unroll
    for (int j = 0; j < 4; j++) acc[i][j] = zv;

  const long kbase = (long)bz * kchunk;
  const uint16_t* As0 = Ab + (long)(m0 + srow) * lda + kbase + skg2 * 8;
  const uint16_t* As1 = Ab + (long)(m0 + 64 + srow) * lda + kbase + skg2 * 8;
  const uint16_t* Bs0 = Bb + (long)(n0 + srow) * ldb + kbase + skg2 * 8;
  const uint16_t* Bs1 = Bb + (long)(n0 + 64 + srow) * ldb + kbase + skg2 * 8;

  int sk = 0, sbuf = 0;
  auto STAGE = [&]() {
    const int bb = sbuf * 16384;
    ASYNC_CP16(As0 + sk, ringB + bb + t * 16);
    ASYNC_CP16(As1 + sk, ringB + bb + 4096 + t * 16);
    ASYNC_CP16(Bs0 + sk, ringB + bb + 8192 + t * 16);
    ASYNC_CP16(Bs1 + sk, ringB + bb + 12288 + t * 16);
    sk += 32;
    if (++sbuf == 3) sbuf = 0;
  };

  STAGE();
  STAGE();

  const int fsw = (fq ^ ((fr >> 1) & 3)) * 8;
  int aof[4], bof[4];
#pragma unroll
  for (int mi = 0; mi < 4; mi++) aof[mi] = (wr * 64 + mi * 16 + fr) * 32 + fsw;
#pragma unroll
  for (int ni = 0; ni < 4; ni++)
    bof[ni] = 4096 + (wc * 64 + ni * 16 + fr) * 32 + fsw;

  int cbuf = 0;
  for (int kt = 0; kt < ksteps; ++kt) {
    if (kt + 2 < ksteps) STAGE();
    if (kt + 2 < ksteps)      asm volatile("s_waitcnt vmcnt(8)" ::: "memory");
    else if (kt + 1 < ksteps) asm volatile("s_waitcnt vmcnt(4)" ::: "memory");
    else                      asm volatile("s_waitcnt vmcnt(0)" ::: "memory");
    __builtin_amdgcn_s_barrier();
    asm volatile("" ::: "memory");
    const uint16_t* base = ring + cbuf * 8192;
    s16x8 af[4], bv[4];
#pragma unroll
    for (int mi = 0; mi < 4; mi++) af[mi] = *(const s16x8*)(base + aof[mi]);
#pragma unroll
    for (int ni = 0; ni < 4; ni++) bv[ni] = *(const s16x8*)(base + bof[ni]);
#pragma unroll
    for (int mi = 0; mi < 4; mi++)
#pragma unroll
      for (int ni = 0; ni < 4; ni++)
        acc[mi][ni] = __builtin_amdgcn_mfma_f32_16x16x32_bf16(
            af[mi], bv[ni], acc[mi][ni], 0, 0, 0);
    asm volatile("s_waitcnt lgkmcnt(0)" ::: "memory");
    __builtin_amdgcn_s_barrier();
    if (++cbuf == 3) cbuf = 0;
  }

  if (EPI == 1) {
#pragma unroll
    for (int mi = 0; mi < 4; mi++) {
      const int hh = wr * 4 + mi;
#pragma unroll
      for (int ni = 0; ni < 4; ni++) {
        const int col = wc * 64 + ni * 16 + fr;
        float p = 0.f;
#pragma unroll
        for (int j = 0; j < 4; j++)
          p += acc[mi][ni][j] * bfr2f(sHq[(fq * 4 + j) * 128 + col]);
        p += __shfl_xor(p, 16);
        p += __shfl_xor(p, 32);
        if (fq == 0)
          pooled[(long)bz * 8192 + hh * 1024 + n0 + col] = f2bfr(p);
      }
    }
  } else if (EPI == 2) {
#pragma unroll
    for (int ni = 0; ni < 4; ni++) {
      const int gn = n0 + wc * 64 + ni * 16 + fr;
      if (gn < nmax) {
#pragma unroll
        for (int mi = 0; mi < 4; mi++)
#pragma unroll
          for (int j = 0; j < 4; j++) {
            const int gm = m0 + wr * 64 + mi * 16 + fq * 4 + j;
            Cf[(long)bz * sCf + (long)gm * ldcf + gn] = acc[mi][ni][j];
          }
      }
    }
  } else {
#pragma unroll
    for (int ni = 0; ni < 4; ni++) {
      const int gn = n0 + wc * 64 + ni * 16 + fr;
#pragma unroll
      for (int mi = 0; mi < 4; mi++)
#pragma unroll
        for (int j = 0; j < 4; j++) {
          const int gm = m0 + wr * 64 + mi * 16 + fq * 4 + j;
          Cbf[(long)bz * sCbf + (long)gm * ldc + gn] = f2bfr(acc[mi][ni][j]);
        }
    }
  }
}

// ---------------- A2[b][h*16+q][c] = bf16(hq[b,q,c] * W[h,c]) ----------------
__global__ __launch_bounds__(256) void mul_hw(const uint16_t* __restrict__ hq,
                                              const uint16_t* __restrict__ watt,
                                              uint16_t* __restrict__ a2) {
  const int idx = blockIdx.x * 256 + threadIdx.x;  // 128*128*128
  const int b = idx >> 14;
  const int m = (idx >> 7) & 127;
  const int c8 = (idx & 127) * 8;
  const int h = m >> 4, q = m & 15;
  s16x8 hv = *(const s16x8*)(hq + ((long)(b * 16 + q)) * 1024 + c8);
  s16x8 wv = *(const s16x8*)(watt + h * 1024 + c8);
  s16x8 o;
#pragma unroll
  for (int j = 0; j < 8; j++)
    o[j] = (short)f2bfr(bfr2f((uint16_t)hv[j]) * bfr2f((uint16_t)wv[j]));
  *(s16x8*)(a2 + (long)idx * 8) = o;
}

// ---------------- in-place softmax over [b][h]: 16x256 bf16 rows -------------
__global__ __launch_bounds__(256) void softmax_att(uint16_t* __restrict__ att) {
  const int b = blockIdx.x >> 3, h = blockIdx.x & 7;
  uint16_t* base = att + (long)b * 32768 + h * 4096;
  const int t = threadIdx.x;
  __shared__ float red[8];
  s16x8 v0 = *(const s16x8*)(base + t * 16);
  s16x8 v1 = *(const s16x8*)(base + t * 16 + 8);
  float f[16];
#pragma unroll
  for (int j = 0; j < 8; j++) {
    f[j] = bfr2f((uint16_t)v0[j]);
    f[8 + j] = bfr2f((uint16_t)v1[j]);
  }
  float mx = f[0];
#pragma unroll
  for (int j = 1; j < 16; j++) mx = fmaxf(mx, f[j]);
#pragma unroll
  for (int d = 1; d < 64; d <<= 1) mx = fmaxf(mx, __shfl_xor(mx, d));
  if ((t & 63) == 0) red[t >> 6] = mx;
  __syncthreads();
  mx = fmaxf(fmaxf(red[0], red[1]), fmaxf(red[2], red[3]));
  float s = 0.f;
#pragma unroll
  for (int j = 0; j < 16; j++) {
    f[j] = __expf(f[j] - mx);
    s += f[j];
  }
#pragma unroll
  for (int d = 1; d < 64; d <<= 1) s += __shfl_xor(s, d);
  if ((t & 63) == 0) red[4 + (t >> 6)] = s;
  __syncthreads();
  const float ri = 1.f / (red[4] + red[5] + red[6] + red[7]);
  s16x8 o0, o1;
#pragma unroll
  for (int j = 0; j < 8; j++) {
    o0[j] = (short)f2bfr(f[j] * ri);
    o1[j] = (short)f2bfr(f[8 + j] * ri);
  }
  *(s16x8*)(base + t * 16) = o0;
  *(s16x8*)(base + t * 16 + 8) = o1;
}

// ---------------- fc partial-sum + bias -> bf16 padded [128][320] ------------
__global__ __launch_bounds__(256) void cvt_out_k(const float* __restrict__ parts,
                                                 const float* __restrict__ fc_b,
                                                 uint16_t* __restrict__ outb) {
  int idx = blockIdx.x * 256 + threadIdx.x;
  if (idx >= 128 * 320) return;
  int m = idx / 320, n = idx % 320;
  float v = 0.f;
  if (n < 300) {
    v = fc_b[n];
#pragma unroll
    for (int ch = 0; ch < 8; ch++) v += parts[ch * 38400 + m * 300 + n];
  }
  outb[idx] = f2bfr(v);
}

// ---------------- row log-softmax over 5000 ----------------
__global__ __launch_bounds__(256) void logsoftmax_k(const float* __restrict__ sim,
                                                    float* __restrict__ out) {
  const int r = blockIdx.x, t = threadIdx.x;
  __shared__ float red[4];
  __shared__ float red2[4];
  const float* x = sim + (long)r * 5000;
  float mx = -1e30f;
  for (int i = t; i < 5000; i += 256) mx = fmaxf(mx, x[i]);
#pragma unroll
  for (int d = 1; d < 64; d <<= 1) mx = fmaxf(mx, __shfl_xor(mx, d));
  if ((t & 63) == 0) red[t >> 6] = mx;
  __syncthreads();
  mx = fmaxf(fmaxf(red[0], red[1]), fmaxf(red[2], red[3]));
  float s = 0.f;
  for (int i = t; i < 5000; i += 256) s += __expf(x[i] - mx);
#pragma unroll
  for (int d = 1; d < 64; d <<= 1) s += __shfl_xor(s, d);
  if ((t & 63) == 0) red2[t >> 6] = s;
  __syncthreads();
  s = red2[0] + red2[1] + red2[2] + red2[3];
  const float lse = mx + logf(s);
  float* o = out + (long)r * 5000;
  for (int i = t; i < 5000; i += 256) o[i] = x[i] - lse;
}

// ---------------------------------------------------------------------------
extern "C" void kernel_launch(void* const* d_in, const int* in_sizes, int n_in,
                              void* d_out, int out_size, void* d_ws, size_t ws_size,
                              hipStream_t stream) {
  (void)in_sizes; (void)n_in; (void)out_size; (void)ws_size;
  const int* he_q = (const int*)d_in[0];
  const int* he_k = (const int*)d_in[1];
  const float* emb_f = (const float*)d_in[2];
  const float* q2h_w = (const float*)d_in[3];
  const float* q2h_b = (const float*)d_in[4];
  const float* k2h_w = (const float*)d_in[5];
  const float* k2h_b = (const float*)d_in[6];
  const float* h2att_w = (const float*)d_in[7];
  // d_in[8] = h2att_b: uniform per-head shift, softmax-invariant -> unused
  const float* fc_w = (const float*)d_in[9];
  const float* fc_b = (const float*)d_in[10];
  const float* glove = (const float*)d_in[11];
  float* out = (float*)d_out;

  char* ws = (char*)d_ws;
  uint16_t* EMB   = (uint16_t*)(ws);              // 50000x320 bf16   32,000,000
  uint16_t* WK    = (uint16_t*)(ws + 32000000);   // 1024x960         1,966,080
  uint16_t* WQ    = (uint16_t*)(ws + 33966080);   // 1024x960         1,966,080
  uint16_t* WATT  = (uint16_t*)(ws + 35932160);   // 8x1024              16,384
  uint16_t* WFC   = (uint16_t*)(ws + 35948544);   // 384x8192         6,291,456
  uint16_t* GLV   = (uint16_t*)(ws + 42240000);   // 5120x320         3,276,800
  uint16_t* HQ    = (uint16_t*)(ws + 45516800);   // 2048x1024        4,194,304
  uint16_t* HS    = (uint16_t*)(ws + 49711104);   // 32768x1024      67,108,864
  uint16_t* HST   = (uint16_t*)(ws + 116819968);  // 128x1024x256    67,108,864
  uint16_t* ATT   = (uint16_t*)(ws + 183928832);  // 128x128x256      8,388,608
  uint16_t* POOL  = (uint16_t*)(ws + 192317440);  // 128x8192         2,097,152
  float*    PARTS = (float*)(ws + 194414592);     // 8x128x300 f32    1,228,800
  uint16_t* OUTB  = (uint16_t*)(ws + 195643392);  // 128x320             81,920
  float*    SIM   = (float*)(ws + 195725312);     // 128x5000 f32     2,560,000
  // A2 aliases the dead EMB+WK region (both dead after the projections):
  uint16_t* A2    = (uint16_t*)(ws);              // 128x128x1024    33,554,432

  // 1) conversions
  cvt_pad300<<<15625, 256, 0, stream>>>(emb_f, EMB, 50000, 50000);
  cvt_pad300<<<960, 256, 0, stream>>>(k2h_w, WK, 3072, 3072);
  cvt_pad300<<<960, 256, 0, stream>>>(q2h_w, WQ, 3072, 3072);
  cvt_pad300<<<1600, 256, 0, stream>>>(glove, GLV, 5120, 5000);
  cvt_plain<<<32, 256, 0, stream>>>(h2att_w, WATT, 8192);
  cvt_fc<<<3072, 256, 0, stream>>>(fc_w, WFC);

  // 2) projections: hs (+fused hsT) and hq in ONE pipelined launch
  gemm_gather2<<<dim3(8, 272), 256, 0, stream>>>(
      he_k, he_q, EMB, WK, WQ, k2h_b, q2h_b, HS, HQ, HST);

  // 3) A2, logits (bf16 into ATT), softmax in-place
  mul_hw<<<8192, 256, 0, stream>>>(HQ, WATT, A2);
  gemm_pipe<3, 1><<<dim3(2, 1, 128), 256, 0, stream>>>(
      A2, 1024, 131072, HS, 1024, 262144, 32, 0,
      ATT, 256, 32768, nullptr, 0, 0, 0, nullptr, nullptr);
  softmax_att<<<1024, 256, 0, stream>>>(ATT);

  // 4) t = att@hs with fused pooled reduce (uses fused HST)
  gemm_pipe<1, 1><<<dim3(8, 1, 128), 256, 0, stream>>>(
      ATT, 256, 32768, HST, 256, 262144, 8, 0,
      nullptr, 0, 0, nullptr, 0, 0, 0, HQ, POOL);

  // 5) fc split-K (8 chunks of 1024)
  gemm_pipe<2, 0><<<dim3(3, 1, 8), 256, 0, stream>>>(
      POOL, 8192, 0, WFC, 8192, 0, 32, 1024,
      nullptr, 0, 0, PARTS, 300, 300, 38400, nullptr, nullptr);

  // 6) sum partials + fc_b -> bf16 padded
  cvt_out_k<<<160, 256, 0, stream>>>(PARTS, fc_b, OUTB);

  // 7) sim = out @ glove^T
  gemm_pipe<2, 0><<<dim3(40, 1, 1), 256, 0, stream>>>(
      OUTB, 320, 0, GLV, 320, 0, 10, 0,
      nullptr, 0, 0, SIM, 5000, 5000, 0, nullptr, nullptr);

  // 8) log-softmax
  logsoftmax_k<<<128, 256, 0, stream>>>(SIM, out);
}

// Round 4
// 214.407 us; speedup vs baseline: 1.4494x; 1.1239x over previous
//
#include <hip/hip_runtime.h>
#include <stdint.h>

// ---------------------------------------------------------------------------
// HAN forward on MI355X (gfx950).  R4: HST materialization removed (the R3
// scatter-store regression); PV GEMM transposes hs in LDS per block instead.
// Gather GEMM keeps ring-3 counted-vmcnt pipeline + swizzle, adds setprio.
// ---------------------------------------------------------------------------

typedef short s16x8 __attribute__((ext_vector_type(8)));
typedef float f32x4 __attribute__((ext_vector_type(4)));

#define ASYNC_CP16(gsrc, ldst)                                                  \
  __builtin_amdgcn_global_load_lds(                                             \
      (const __attribute__((address_space(1))) void*)(gsrc),                    \
      (__attribute__((address_space(3))) void*)(ldst), 16, 0, 0)

__device__ __forceinline__ float bfr2f(uint16_t u) {
  return __builtin_bit_cast(float, (uint32_t)u << 16);
}
__device__ __forceinline__ uint16_t f2bfr(float f) {
  uint32_t u = __builtin_bit_cast(uint32_t, f);
  u += 0x7fffu + ((u >> 16) & 1u);   // RNE
  return (uint16_t)(u >> 16);
}

// ---------------- conversion kernels ----------------

__global__ __launch_bounds__(256) void cvt_pad300(const float* __restrict__ src,
                                                  uint16_t* __restrict__ dst,
                                                  int rows_out, int rows_src) {
  int idx = blockIdx.x * 256 + threadIdx.x;
  if (idx >= rows_out * 80) return;
  int r = idx / 80, j = idx % 80;
  float4 v = make_float4(0.f, 0.f, 0.f, 0.f);
  if (r < rows_src && j < 75) v = *(const float4*)(src + (size_t)r * 300 + j * 4);
  ushort4 o;
  o.x = f2bfr(v.x); o.y = f2bfr(v.y); o.z = f2bfr(v.z); o.w = f2bfr(v.w);
  *(ushort4*)(dst + (size_t)r * 320 + j * 4) = o;
}

__global__ __launch_bounds__(256) void cvt_plain(const float* __restrict__ src,
                                                 uint16_t* __restrict__ dst, int n) {
  int i = blockIdx.x * 256 + threadIdx.x;
  if (i < n) dst[i] = f2bfr(src[i]);
}

// fc_w [300][8192] f32 -> [384][8192] bf16 (rows >=300 zero)
__global__ __launch_bounds__(256) void cvt_fc(const float* __restrict__ src,
                                              uint16_t* __restrict__ dst) {
  int i4 = blockIdx.x * 256 + threadIdx.x;  // < 384*2048
  int pos = i4 * 4;
  int r = pos >> 13, c = pos & 8191;
  float4 v = make_float4(0.f, 0.f, 0.f, 0.f);
  if (r < 300) v = *(const float4*)(src + (size_t)r * 8192 + c);
  ushort4 o;
  o.x = f2bfr(v.x); o.y = f2bfr(v.y); o.z = f2bfr(v.z); o.w = f2bfr(v.w);
  *(ushort4*)(dst + (size_t)r * 8192 + c) = o;
}

// ============ pipelined gather-GEMM: hs (256 m-tiles) + hq (16 m-tiles) =====
// C[128m][1024] = gather(emb,he)@W^T + b,  K=960 (3 nodes x 320), BK=32.
__global__ __launch_bounds__(256) void gemm_gather2(
    const int* __restrict__ heK, const int* __restrict__ heQ,
    const uint16_t* __restrict__ emb,
    const uint16_t* __restrict__ WKp, const uint16_t* __restrict__ WQp,
    const float* __restrict__ bK, const float* __restrict__ bQ,
    uint16_t* __restrict__ HS, uint16_t* __restrict__ HQ) {
  __shared__ uint16_t ring[3 * 8192];  // 3 bufs x (A[128][32] + B[128][32])
  __shared__ int sIdx[384];
  char* ringB = (char*)ring;

  const int t = threadIdx.x;
  const int lane = t & 63, wave = t >> 6;
  const int wr = wave >> 1, wc = wave & 1;
  const int fr = lane & 15, fq = lane >> 4;
  const int srow = t >> 2, skg = t & 3;
  const int skg2 = skg ^ ((srow >> 1) & 3);  // inverse LDS swizzle on source

  // bijective XCD-chunk swizzle; grid = (8, 272), nwg = 2176
  const int v = blockIdx.x + 8 * blockIdx.y;
  const int w = (v & 7) * 272 + (v >> 3);
  const int bx = w & 7, by = w >> 3;
  const int n0 = bx * 128;
  const bool isK = by < 256;
  const int m0 = (isK ? by : by - 256) * 128;
  const int* he = isK ? heK : heQ;
  const uint16_t* W = isK ? WKp : WQp;
  const float* bias = isK ? bK : bQ;
  uint16_t* C = isK ? HS : HQ;

  for (int i = t; i < 384; i += 256) sIdx[i] = he[(long)m0 * 3 + i];
  __syncthreads();

  uint32_t ea[2][3];
#pragma unroll
  for (int h = 0; h < 2; h++)
#pragma unroll
    for (int nd = 0; nd < 3; nd++)
      ea[h][nd] =
          (uint32_t)sIdx[(h * 64 + srow) * 3 + nd] * 640u + (uint32_t)(skg2 * 16);
  const uint16_t* Wr0 = W + (long)(n0 + srow) * 960 + skg2 * 8;
  const uint16_t* Wr1 = W + (long)(n0 + 64 + srow) * 960 + skg2 * 8;

  f32x4 zv = {0.f, 0.f, 0.f, 0.f};
  f32x4 acc[4][4];
#pragma unroll
  for (int i = 0; i < 4; i++)
#pragma unroll
    for (int j = 0; j < 4; j++) acc[i][j] = zv;

  int snd = 0, skk = 0, sk = 0, sbuf = 0;
  auto STAGE = [&]() {
    const int bb = sbuf * 16384;
    const uint32_t e0 = snd == 0 ? ea[0][0] : (snd == 1 ? ea[0][1] : ea[0][2]);
    const uint32_t e1 = snd == 0 ? ea[1][0] : (snd == 1 ? ea[1][1] : ea[1][2]);
    ASYNC_CP16((const char*)emb + e0 + skk * 64, ringB + bb + t * 16);
    ASYNC_CP16((const char*)emb + e1 + skk * 64, ringB + bb + 4096 + t * 16);
    ASYNC_CP16(Wr0 + sk, ringB + bb + 8192 + t * 16);
    ASYNC_CP16(Wr1 + sk, ringB + bb + 12288 + t * 16);
    sk += 32;
    if (++skk == 10) { skk = 0; ++snd; }
    if (++sbuf == 3) sbuf = 0;
  };

  STAGE();
  STAGE();

  // lane-constant swizzled fragment offsets (elements)
  const int fsw = (fq ^ ((fr >> 1) & 3)) * 8;
  int aof[4], bof[4];
#pragma unroll
  for (int mi = 0; mi < 4; mi++) aof[mi] = (wr * 64 + mi * 16 + fr) * 32 + fsw;
#pragma unroll
  for (int ni = 0; ni < 4; ni++)
    bof[ni] = 4096 + (wc * 64 + ni * 16 + fr) * 32 + fsw;

  int cbuf = 0;
  for (int kt = 0; kt < 30; ++kt) {
    if (kt < 28) STAGE();
    if (kt < 28)      asm volatile("s_waitcnt vmcnt(8)" ::: "memory");
    else if (kt < 29) asm volatile("s_waitcnt vmcnt(4)" ::: "memory");
    else              asm volatile("s_waitcnt vmcnt(0)" ::: "memory");
    __builtin_amdgcn_s_barrier();
    asm volatile("" ::: "memory");
    const uint16_t* base = ring + cbuf * 8192;
    s16x8 af[4], bv[4];
#pragma unroll
    for (int mi = 0; mi < 4; mi++) af[mi] = *(const s16x8*)(base + aof[mi]);
#pragma unroll
    for (int ni = 0; ni < 4; ni++) bv[ni] = *(const s16x8*)(base + bof[ni]);
    __builtin_amdgcn_s_setprio(1);
#pragma unroll
    for (int mi = 0; mi < 4; mi++)
#pragma unroll
      for (int ni = 0; ni < 4; ni++)
        acc[mi][ni] = __builtin_amdgcn_mfma_f32_16x16x32_bf16(
            af[mi], bv[ni], acc[mi][ni], 0, 0, 0);
    __builtin_amdgcn_s_setprio(0);
    asm volatile("s_waitcnt lgkmcnt(0)" ::: "memory");
    __builtin_amdgcn_s_barrier();
    if (++cbuf == 3) cbuf = 0;
  }

  // epilogue: C = acc + bias (scalar stores, R2-proven)
#pragma unroll
  for (int ni = 0; ni < 4; ni++) {
    const int gn = n0 + wc * 64 + ni * 16 + fr;
    const float bval = bias[gn];
#pragma unroll
    for (int mi = 0; mi < 4; mi++) {
      const int gmb = m0 + wr * 64 + mi * 16 + fq * 4;
      uint16_t* cp = C + (long)gmb * 1024 + gn;
      cp[0]    = f2bfr(acc[mi][ni][0] + bval);
      cp[1024] = f2bfr(acc[mi][ni][1] + bval);
      cp[2048] = f2bfr(acc[mi][ni][2] + bval);
      cp[3072] = f2bfr(acc[mi][ni][3] + bval);
    }
  }
}

// ============ pipelined plain GEMM: C = A @ Bt^T ============================
// EPI: 2 = f32 store (col guard); 3 = bf16 store.  SWZ: XCD swizzle over (x,z)
template <int EPI, int SWZ>
__global__ __launch_bounds__(256) void gemm_pipe(
    const uint16_t* __restrict__ A, int lda, long sAb,
    const uint16_t* __restrict__ Bt, int ldb, long sBb,
    int ksteps, int kchunk,
    uint16_t* __restrict__ Cbf, int ldc, long sCbf,
    float* __restrict__ Cf, int ldcf, int nmax, long sCf) {
  __shared__ uint16_t ring[3 * 8192];
  char* ringB = (char*)ring;

  const int t = threadIdx.x;
  const int lane = t & 63, wave = t >> 6;
  const int wr = wave >> 1, wc = wave & 1;
  const int fr = lane & 15, fq = lane >> 4;
  const int srow = t >> 2, skg = t & 3;
  const int skg2 = skg ^ ((srow >> 1) & 3);

  int bx = blockIdx.x, bz = blockIdx.z;
  if (SWZ) {
    const int nwg = gridDim.x * gridDim.z;
    const int v = bx + gridDim.x * bz;
    const int w = (v & 7) * (nwg >> 3) + (v >> 3);
    bx = w % gridDim.x;
    bz = w / gridDim.x;
  }
  const int m0 = blockIdx.y * 128, n0 = bx * 128;
  const uint16_t* Ab = A + (long)bz * sAb;
  const uint16_t* Bb = Bt + (long)bz * sBb;

  f32x4 zv = {0.f, 0.f, 0.f, 0.f};
  f32x4 acc[4][4];
#pragma unroll
  for (int i = 0; i < 4; i++)
#pragma unroll
    for (int j = 0; j < 4; j++) acc[i][j] = zv;

  const long kbase = (long)bz * kchunk;
  const uint16_t* As0 = Ab + (long)(m0 + srow) * lda + kbase + skg2 * 8;
  const uint16_t* As1 = Ab + (long)(m0 + 64 + srow) * lda + kbase + skg2 * 8;
  const uint16_t* Bs0 = Bb + (long)(n0 + srow) * ldb + kbase + skg2 * 8;
  const uint16_t* Bs1 = Bb + (long)(n0 + 64 + srow) * ldb + kbase + skg2 * 8;

  int sk = 0, sbuf = 0;
  auto STAGE = [&]() {
    const int bb = sbuf * 16384;
    ASYNC_CP16(As0 + sk, ringB + bb + t * 16);
    ASYNC_CP16(As1 + sk, ringB + bb + 4096 + t * 16);
    ASYNC_CP16(Bs0 + sk, ringB + bb + 8192 + t * 16);
    ASYNC_CP16(Bs1 + sk, ringB + bb + 12288 + t * 16);
    sk += 32;
    if (++sbuf == 3) sbuf = 0;
  };

  STAGE();
  STAGE();

  const int fsw = (fq ^ ((fr >> 1) & 3)) * 8;
  int aof[4], bof[4];
#pragma unroll
  for (int mi = 0; mi < 4; mi++) aof[mi] = (wr * 64 + mi * 16 + fr) * 32 + fsw;
#pragma unroll
  for (int ni = 0; ni < 4; ni++)
    bof[ni] = 4096 + (wc * 64 + ni * 16 + fr) * 32 + fsw;

  int cbuf = 0;
  for (int kt = 0; kt < ksteps; ++kt) {
    if (kt + 2 < ksteps) STAGE();
    if (kt + 2 < ksteps)      asm volatile("s_waitcnt vmcnt(8)" ::: "memory");
    else if (kt + 1 < ksteps) asm volatile("s_waitcnt vmcnt(4)" ::: "memory");
    else                      asm volatile("s_waitcnt vmcnt(0)" ::: "memory");
    __builtin_amdgcn_s_barrier();
    asm volatile("" ::: "memory");
    const uint16_t* base = ring + cbuf * 8192;
    s16x8 af[4], bv[4];
#pragma unroll
    for (int mi = 0; mi < 4; mi++) af[mi] = *(const s16x8*)(base + aof[mi]);
#pragma unroll
    for (int ni = 0; ni < 4; ni++) bv[ni] = *(const s16x8*)(base + bof[ni]);
#pragma unroll
    for (int mi = 0; mi < 4; mi++)
#pragma unroll
      for (int ni = 0; ni < 4; ni++)
        acc[mi][ni] = __builtin_amdgcn_mfma_f32_16x16x32_bf16(
            af[mi], bv[ni], acc[mi][ni], 0, 0, 0);
    asm volatile("s_waitcnt lgkmcnt(0)" ::: "memory");
    __builtin_amdgcn_s_barrier();
    if (++cbuf == 3) cbuf = 0;
  }

  if (EPI == 2) {
#pragma unroll
    for (int ni = 0; ni < 4; ni++) {
      const int gn = n0 + wc * 64 + ni * 16 + fr;
      if (gn < nmax) {
#pragma unroll
        for (int mi = 0; mi < 4; mi++)
#pragma unroll
          for (int j = 0; j < 4; j++) {
            const int gm = m0 + wr * 64 + mi * 16 + fq * 4 + j;
            Cf[(long)bz * sCf + (long)gm * ldcf + gn] = acc[mi][ni][j];
          }
      }
    }
  } else {
#pragma unroll
    for (int ni = 0; ni < 4; ni++) {
      const int gn = n0 + wc * 64 + ni * 16 + fr;
#pragma unroll
      for (int mi = 0; mi < 4; mi++)
#pragma unroll
        for (int j = 0; j < 4; j++) {
          const int gm = m0 + wr * 64 + mi * 16 + fq * 4 + j;
          Cbf[(long)bz * sCbf + (long)gm * ldc + gn] = f2bfr(acc[mi][ni][j]);
        }
    }
  }
}

// ============ PV GEMM with in-LDS hs transpose + fused pooled ===============
// Per block (c-tile n0, batch b): t[m=h*16+q][c] = sum_s att[m][s] hs[s][c];
// pooled[b,h,c] = sum_q hq[q,c] * t[h*16+q][c].
__global__ __launch_bounds__(256) void gemm_pv(
    const uint16_t* __restrict__ att, const uint16_t* __restrict__ hs,
    const uint16_t* __restrict__ hqp, uint16_t* __restrict__ pooled) {
  __shared__ uint16_t sT[128 * 264];  // hsT chunk [c 128][s 256 pad->264]
  __shared__ uint16_t sA[4096];       // att tile [128][32]
  __shared__ uint16_t sHq[2048];      // hq [16 q][128 c]

  const int t = threadIdx.x;
  const int lane = t & 63, wave = t >> 6;
  const int wr = wave >> 1, wc = wave & 1;
  const int fr = lane & 15, fq = lane >> 4;
  const int srow = t >> 2, skg = t & 3;
  const int skg2 = skg ^ ((srow >> 1) & 3);

  // XCD swizzle over (x=8 c-tiles, z=128 b): groups same-b tiles per XCD
  int bx = blockIdx.x, bz = blockIdx.z;
  {
    const int v = bx + 8 * bz;
    const int w = (v & 7) * 128 + (v >> 3);
    bx = w & 7;
    bz = w >> 3;
  }
  const int n0 = bx * 128;

  // ---- build hsT chunk: read hs[b][s][n0..n0+127] -> sT[c][s] ----
  const uint16_t* hsb = hs + (long)bz * 262144;
  const int sloc = t & 15, c8 = t >> 4;  // c8: 0..15
  s16x8 vv[16];
#pragma unroll
  for (int p = 0; p < 16; p++)
    vv[p] = *(const s16x8*)(hsb + (long)(p * 16 + sloc) * 1024 + n0 + c8 * 8);
  // hq tile
  *(s16x8*)(sHq + (t >> 4) * 128 + (t & 15) * 8) =
      *(const s16x8*)(hqp + (long)bz * 16384 + (long)(t >> 4) * 1024 + n0 +
                      (t & 15) * 8);
#pragma unroll
  for (int p = 0; p < 16; p++) {
    const int s = p * 16 + sloc;
#pragma unroll
    for (int j = 0; j < 8; j++)
      sT[(c8 * 8 + j) * 264 + s] = (uint16_t)vv[p][j];
  }
  __syncthreads();

  f32x4 zv = {0.f, 0.f, 0.f, 0.f};
  f32x4 acc[4][4];
#pragma unroll
  for (int i = 0; i < 4; i++)
#pragma unroll
    for (int j = 0; j < 4; j++) acc[i][j] = zv;

  const uint16_t* As0 = att + (long)bz * 32768 + (long)srow * 256 + skg2 * 8;
  const uint16_t* As1 = att + (long)bz * 32768 + (long)(64 + srow) * 256 + skg2 * 8;

  const int fsw = (fq ^ ((fr >> 1) & 3)) * 8;
  int aof[4];
#pragma unroll
  for (int mi = 0; mi < 4; mi++) aof[mi] = (wr * 64 + mi * 16 + fr) * 32 + fsw;

  for (int kt = 0; kt < 8; ++kt) {
    ASYNC_CP16(As0 + kt * 32, (char*)sA + t * 16);
    ASYNC_CP16(As1 + kt * 32, (char*)sA + 4096 + t * 16);
    __syncthreads();  // drains vmcnt(0): sA ready
    s16x8 af[4], bv[4];
#pragma unroll
    for (int mi = 0; mi < 4; mi++) af[mi] = *(const s16x8*)(sA + aof[mi]);
#pragma unroll
    for (int ni = 0; ni < 4; ni++)
      bv[ni] = *(const s16x8*)(sT + (wc * 64 + ni * 16 + fr) * 264 + kt * 32 +
                               fq * 8);
    __builtin_amdgcn_s_setprio(1);
#pragma unroll
    for (int mi = 0; mi < 4; mi++)
#pragma unroll
      for (int ni = 0; ni < 4; ni++)
        acc[mi][ni] = __builtin_amdgcn_mfma_f32_16x16x32_bf16(
            af[mi], bv[ni], acc[mi][ni], 0, 0, 0);
    __builtin_amdgcn_s_setprio(0);
    __syncthreads();  // frags consumed before next-stage overwrite
  }

  // pooled epilogue: p = acc * hq, reduce over q (fq*4+j) via shfl
#pragma unroll
  for (int mi = 0; mi < 4; mi++) {
    const int hh = wr * 4 + mi;
#pragma unroll
    for (int ni = 0; ni < 4; ni++) {
      const int col = wc * 64 + ni * 16 + fr;
      float p = 0.f;
#pragma unroll
      for (int j = 0; j < 4; j++)
        p += acc[mi][ni][j] * bfr2f(sHq[(fq * 4 + j) * 128 + col]);
      p += __shfl_xor(p, 16);
      p += __shfl_xor(p, 32);
      if (fq == 0)
        pooled[(long)bz * 8192 + hh * 1024 + n0 + col] = f2bfr(p);
    }
  }
}

// ---------------- A2[b][h*16+q][c] = bf16(hq[b,q,c] * W[h,c]) ----------------
__global__ __launch_bounds__(256) void mul_hw(const uint16_t* __restrict__ hq,
                                              const uint16_t* __restrict__ watt,
                                              uint16_t* __restrict__ a2) {
  const int idx = blockIdx.x * 256 + threadIdx.x;  // 128*128*128
  const int b = idx >> 14;
  const int m = (idx >> 7) & 127;
  const int c8 = (idx & 127) * 8;
  const int h = m >> 4, q = m & 15;
  s16x8 hv = *(const s16x8*)(hq + ((long)(b * 16 + q)) * 1024 + c8);
  s16x8 wv = *(const s16x8*)(watt + h * 1024 + c8);
  s16x8 o;
#pragma unroll
  for (int j = 0; j < 8; j++)
    o[j] = (short)f2bfr(bfr2f((uint16_t)hv[j]) * bfr2f((uint16_t)wv[j]));
  *(s16x8*)(a2 + (long)idx * 8) = o;
}

// ---------------- in-place softmax over [b][h]: 16x256 bf16 rows -------------
__global__ __launch_bounds__(256) void softmax_att(uint16_t* __restrict__ att) {
  const int b = blockIdx.x >> 3, h = blockIdx.x & 7;
  uint16_t* base = att + (long)b * 32768 + h * 4096;
  const int t = threadIdx.x;
  __shared__ float red[8];
  s16x8 v0 = *(const s16x8*)(base + t * 16);
  s16x8 v1 = *(const s16x8*)(base + t * 16 + 8);
  float f[16];
#pragma unroll
  for (int j = 0; j < 8; j++) {
    f[j] = bfr2f((uint16_t)v0[j]);
    f[8 + j] = bfr2f((uint16_t)v1[j]);
  }
  float mx = f[0];
#pragma unroll
  for (int j = 1; j < 16; j++) mx = fmaxf(mx, f[j]);
#pragma unroll
  for (int d = 1; d < 64; d <<= 1) mx = fmaxf(mx, __shfl_xor(mx, d));
  if ((t & 63) == 0) red[t >> 6] = mx;
  __syncthreads();
  mx = fmaxf(fmaxf(red[0], red[1]), fmaxf(red[2], red[3]));
  float s = 0.f;
#pragma unroll
  for (int j = 0; j < 16; j++) {
    f[j] = __expf(f[j] - mx);
    s += f[j];
  }
#pragma unroll
  for (int d = 1; d < 64; d <<= 1) s += __shfl_xor(s, d);
  if ((t & 63) == 0) red[4 + (t >> 6)] = s;
  __syncthreads();
  const float ri = 1.f / (red[4] + red[5] + red[6] + red[7]);
  s16x8 o0, o1;
#pragma unroll
  for (int j = 0; j < 8; j++) {
    o0[j] = (short)f2bfr(f[j] * ri);
    o1[j] = (short)f2bfr(f[8 + j] * ri);
  }
  *(s16x8*)(base + t * 16) = o0;
  *(s16x8*)(base + t * 16 + 8) = o1;
}

// ---------------- fc partial-sum + bias -> bf16 padded [128][320] ------------
__global__ __launch_bounds__(256) void cvt_out_k(const float* __restrict__ parts,
                                                 const float* __restrict__ fc_b,
                                                 uint16_t* __restrict__ outb) {
  int idx = blockIdx.x * 256 + threadIdx.x;
  if (idx >= 128 * 320) return;
  int m = idx / 320, n = idx % 320;
  float v = 0.f;
  if (n < 300) {
    v = fc_b[n];
#pragma unroll
    for (int ch = 0; ch < 8; ch++) v += parts[ch * 38400 + m * 300 + n];
  }
  outb[idx] = f2bfr(v);
}

// ---------------- row log-softmax over 5000 ----------------
__global__ __launch_bounds__(256) void logsoftmax_k(const float* __restrict__ sim,
                                                    float* __restrict__ out) {
  const int r = blockIdx.x, t = threadIdx.x;
  __shared__ float red[4];
  __shared__ float red2[4];
  const float* x = sim + (long)r * 5000;
  float mx = -1e30f;
  for (int i = t; i < 5000; i += 256) mx = fmaxf(mx, x[i]);
#pragma unroll
  for (int d = 1; d < 64; d <<= 1) mx = fmaxf(mx, __shfl_xor(mx, d));
  if ((t & 63) == 0) red[t >> 6] = mx;
  __syncthreads();
  mx = fmaxf(fmaxf(red[0], red[1]), fmaxf(red[2], red[3]));
  float s = 0.f;
  for (int i = t; i < 5000; i += 256) s += __expf(x[i] - mx);
#pragma unroll
  for (int d = 1; d < 64; d <<= 1) s += __shfl_xor(s, d);
  if ((t & 63) == 0) red2[t >> 6] = s;
  __syncthreads();
  s = red2[0] + red2[1] + red2[2] + red2[3];
  const float lse = mx + logf(s);
  float* o = out + (long)r * 5000;
  for (int i = t; i < 5000; i += 256) o[i] = x[i] - lse;
}

// ---------------------------------------------------------------------------
extern "C" void kernel_launch(void* const* d_in, const int* in_sizes, int n_in,
                              void* d_out, int out_size, void* d_ws, size_t ws_size,
                              hipStream_t stream) {
  (void)in_sizes; (void)n_in; (void)out_size; (void)ws_size;
  const int* he_q = (const int*)d_in[0];
  const int* he_k = (const int*)d_in[1];
  const float* emb_f = (const float*)d_in[2];
  const float* q2h_w = (const float*)d_in[3];
  const float* q2h_b = (const float*)d_in[4];
  const float* k2h_w = (const float*)d_in[5];
  const float* k2h_b = (const float*)d_in[6];
  const float* h2att_w = (const float*)d_in[7];
  // d_in[8] = h2att_b: uniform per-head shift, softmax-invariant -> unused
  const float* fc_w = (const float*)d_in[9];
  const float* fc_b = (const float*)d_in[10];
  const float* glove = (const float*)d_in[11];
  float* out = (float*)d_out;

  char* ws = (char*)d_ws;
  uint16_t* EMB   = (uint16_t*)(ws);              // 50000x320 bf16   32,000,000
  uint16_t* WK    = (uint16_t*)(ws + 32000000);   // 1024x960         1,966,080
  uint16_t* WQ    = (uint16_t*)(ws + 33966080);   // 1024x960         1,966,080
  uint16_t* WATT  = (uint16_t*)(ws + 35932160);   // 8x1024              16,384
  uint16_t* WFC   = (uint16_t*)(ws + 35948544);   // 384x8192         6,291,456
  uint16_t* GLV   = (uint16_t*)(ws + 42240000);   // 5120x320         3,276,800
  uint16_t* HQ    = (uint16_t*)(ws + 45516800);   // 2048x1024        4,194,304
  uint16_t* HS    = (uint16_t*)(ws + 49711104);   // 32768x1024      67,108,864
  uint16_t* ATT   = (uint16_t*)(ws + 183928832);  // 128x128x256      8,388,608
  uint16_t* POOL  = (uint16_t*)(ws + 192317440);  // 128x8192         2,097,152
  float*    PARTS = (float*)(ws + 194414592);     // 8x128x300 f32    1,228,800
  uint16_t* OUTB  = (uint16_t*)(ws + 195643392);  // 128x320             81,920
  float*    SIM   = (float*)(ws + 195725312);     // 128x5000 f32     2,560,000
  // A2 aliases the dead EMB+WK region (both dead after the projections):
  uint16_t* A2    = (uint16_t*)(ws);              // 128x128x1024    33,554,432

  // 1) conversions
  cvt_pad300<<<15625, 256, 0, stream>>>(emb_f, EMB, 50000, 50000);
  cvt_pad300<<<960, 256, 0, stream>>>(k2h_w, WK, 3072, 3072);
  cvt_pad300<<<960, 256, 0, stream>>>(q2h_w, WQ, 3072, 3072);
  cvt_pad300<<<1600, 256, 0, stream>>>(glove, GLV, 5120, 5000);
  cvt_plain<<<32, 256, 0, stream>>>(h2att_w, WATT, 8192);
  cvt_fc<<<3072, 256, 0, stream>>>(fc_w, WFC);

  // 2) projections: hs and hq in ONE pipelined launch (no HST)
  gemm_gather2<<<dim3(8, 272), 256, 0, stream>>>(
      he_k, he_q, EMB, WK, WQ, k2h_b, q2h_b, HS, HQ);

  // 3) A2, logits (bf16 into ATT), softmax in-place
  mul_hw<<<8192, 256, 0, stream>>>(HQ, WATT, A2);
  gemm_pipe<3, 1><<<dim3(2, 1, 128), 256, 0, stream>>>(
      A2, 1024, 131072, HS, 1024, 262144, 32, 0,
      ATT, 256, 32768, nullptr, 0, 0, 0);
  softmax_att<<<1024, 256, 0, stream>>>(ATT);

  // 4) PV + pooled (in-LDS hs transpose; no HST materialization)
  gemm_pv<<<dim3(8, 1, 128), 256, 0, stream>>>(ATT, HS, HQ, POOL);

  // 5) fc split-K (8 chunks of 1024)
  gemm_pipe<2, 0><<<dim3(3, 1, 8), 256, 0, stream>>>(
      POOL, 8192, 0, WFC, 8192, 0, 32, 1024,
      nullptr, 0, 0, PARTS, 300, 300, 38400);

  // 6) sum partials + fc_b -> bf16 padded
  cvt_out_k<<<160, 256, 0, stream>>>(PARTS, fc_b, OUTB);

  // 7) sim = out @ glove^T
  gemm_pipe<2, 0><<<dim3(40, 1, 1), 256, 0, stream>>>(
      OUTB, 320, 0, GLV, 320, 0, 10, 0,
      nullptr, 0, 0, SIM, 5000, 5000, 0);

  // 8) log-softmax
  logsoftmax_k<<<128, 256, 0, stream>>>(SIM, out);
}